// Round 14
// baseline (601.899 us; speedup 1.0000x reference)
//
#include <hip/hip_runtime.h>
#include <stdint.h>
#include <math.h>

#define NROW 8192
// dims: IN=32, G=16, H1=32, H2=16, LSTM_HID = 32
// out: actions[8192], h_out @ 8192, c_out @ 270336

// ---------------- workspace layout (floats, in d_ws; ws_size = 1 GiB) ----------------
constexpr size_t W_FP  = 0;                              // fwd partials [16][8192][32]
constexpr size_t W_GP  = W_FP  + (size_t)16*NROW*32;     // tr  partials [64][8192][32]
constexpr size_t W_RSP = W_GP  + (size_t)64*NROW*32;     // rowsum partials [16][8192]
constexpr size_t W_CSP = W_RSP + (size_t)16*NROW;        // colsum partials [64][8192]
constexpr size_t W_RS  = W_CSP + (size_t)64*NROW;        // rowsum [8192]
constexpr size_t W_CS  = W_RS  + NROW;                   // colsum [8192]
constexpr size_t W_V1  = W_CS  + NROW;                   // v1 [8192][32]
constexpr size_t W_V2  = W_V1  + (size_t)NROW*32;        // v2 [8192][16]
constexpr size_t W_U1  = W_V2  + (size_t)NROW*16;        // u1 [16]
constexpr size_t W_U2  = W_U1  + 16;                     // u2 [16]
constexpr size_t W_MLP = W_U2  + 16;                     // l1-mean partials [256][96]
constexpr size_t W_U2P = W_MLP + (size_t)256*96;         // u2 partials [512][16]
constexpr size_t W_XT1 = W_U2P + (size_t)512*16;         // x^T packed [32][8192] u32
constexpr size_t W_XT2 = W_XT1 + (size_t)32*NROW;        // v1^T packed [32][8192] u32
constexpr size_t W_XT3 = W_XT2 + (size_t)32*NROW;        // v2^T packed [16][8192] u32

typedef float f32x4 __attribute__((ext_vector_type(4)));
typedef short s16x8 __attribute__((ext_vector_type(8)));

__device__ __forceinline__ float leaky(float v) { return v >= 0.f ? v : 0.01f * v; }
__device__ __forceinline__ float sigf(float v) { return 1.f / (1.f + __expf(-v)); }
__device__ __forceinline__ double leakyd(double v) { return v >= 0. ? v : 0.01 * v; }

// lgkm-only barrier: orders LDS, leaves global loads/stores in flight
__device__ __forceinline__ void bar_lds() {
  asm volatile("s_waitcnt lgkmcnt(0)" ::: "memory");
  __builtin_amdgcn_s_barrier();
}

// f32 -> bf16 (RNE)
__device__ __forceinline__ uint32_t bf16rne(float x) {
  uint32_t b = __float_as_uint(x);
  return (b + 0x7FFFu + ((b >> 16) & 1u)) >> 16;
}
__device__ __forceinline__ float bf2f(short s) {
  return __uint_as_float(((uint32_t)(uint16_t)s) << 16);
}
// pack f32 -> (hi bf16) | (lo bf16 << 16)
__device__ __forceinline__ uint32_t packHL(float x) {
  const uint32_t hb = bf16rne(x);
  const float hf = __uint_as_float(hb << 16);
  const uint32_t lb = bf16rne(x - hf);
  return hb | (lb << 16);
}
__device__ __forceinline__ void cvt_hilo8(const float v[8], s16x8& h, s16x8& l) {
  #pragma unroll
  for (int j = 0; j < 8; ++j) {
    const uint32_t hb = bf16rne(v[j]);
    const float hf = __uint_as_float(hb << 16);
    h[j] = (short)hb;
    l[j] = (short)bf16rne(v[j] - hf);
  }
}
__device__ __forceinline__ void unpack8(const uint32_t u[8], s16x8& h, s16x8& l) {
  #pragma unroll
  for (int j = 0; j < 8; ++j) { h[j] = (short)(u[j] & 0xffffu); l[j] = (short)(u[j] >> 16); }
}
__device__ __forceinline__ void ld8(const float* p, float v[8]) {
  const float4 a = *(const float4*)p;
  const float4 b = *(const float4*)(p + 4);
  v[0]=a.x; v[1]=a.y; v[2]=a.z; v[3]=a.w; v[4]=b.x; v[5]=b.y; v[6]=b.z; v[7]=b.w;
}
// load 8 packed u32 from XT and unpack to hi/lo fragments
__device__ __forceinline__ void ldXT8(const uint32_t* p, s16x8& h, s16x8& l) {
  const uint4 ua = *(const uint4*)p;
  const uint4 ub = *(const uint4*)(p + 4);
  const uint32_t u[8] = {ua.x, ua.y, ua.z, ua.w, ub.x, ub.y, ub.z, ub.w};
  unpack8(u, h, l);
}

// JAX threefry2x32 (20 rounds), key = (0, 42)
__device__ __forceinline__ void threefry(uint32_t x0, uint32_t x1, uint32_t& o0, uint32_t& o1) {
  const uint32_t ks0 = 0u, ks1 = 42u;
  const uint32_t ks2 = ks0 ^ ks1 ^ 0x1BD11BDAu;
  uint32_t ks[3] = {ks0, ks1, ks2};
  const int R0[4] = {13, 15, 26, 6};
  const int R1[4] = {17, 29, 16, 24};
  x0 += ks[0]; x1 += ks[1];
  #pragma unroll
  for (int g = 0; g < 5; ++g) {
    const int* R = (g & 1) ? R1 : R0;
    #pragma unroll
    for (int i = 0; i < 4; ++i) {
      x0 += x1;
      x1 = (x1 << R[i]) | (x1 >> (32 - R[i]));
      x1 ^= x0;
    }
    x0 += ks[(g + 1) % 3];
    x1 += ks[(g + 2) % 3] + (uint32_t)(g + 1);
  }
  o0 = x0; o1 = x1;
}

// ---------------- tiny transpose+pack: X [8192][C] f32 -> XT [C][8192] u32 ----------------
template <int C>
__global__ __launch_bounds__(256) void k_xt(const float* __restrict__ X, uint32_t* __restrict__ XT) {
  const int i = blockIdx.x * 256 + threadIdx.x;
  #pragma unroll 4
  for (int c = 0; c < C; ++c)
    XT[(size_t)c * NROW + i] = packHL(X[(size_t)i * C + c]);
}

// ---------------- fused MFMA GEMM v14: dbuf aP + one lgkm-barrier/chunk; B from XT (L2) ----------------
// Fp[kz]=adj@X (rows), Gp[iz]=adj^T@X (cols). bf16 hi/lo split (3 MFMA) ~ f32 accuracy.
// grid (64 iz, 16 kz), block 256 = 4 waves. Tile 128 i x 512 k, 16 chunks of 32 k.
// waves 0,1: fwd (A global f32 + cvt; B from XT global, L2-hot).
// waves 2,3: tr  (A from aP[cur] packed-u32 k-major LDS; B from XT global).
// Per chunk: compute(aP[cur]) || ds_write next chunk -> aP[cur^1] || global loads 2 ahead; bar_lds().
template <int C, bool SUMS>
__global__ __launch_bounds__(256) void k_gemm(const float* __restrict__ adj,
                                              const uint32_t* __restrict__ XT,
                                              float* __restrict__ Fp,
                                              float* __restrict__ Gp,
                                              float* __restrict__ rsP,
                                              float* __restrict__ csP) {
  constexpr int NT = C / 16;
  __shared__ alignas(16) uint32_t aP[2][32 * 132];   // adj chunk k-major packed (hi|lo<<16)
  const int t = threadIdx.x;
  const int iz = blockIdx.x;      // 0..63
  const int kz = blockIdx.y;      // 0..15
  const int I0 = iz * 128;
  const int K0 = kz * 512;
  const int lane = t & 63;
  const int wid = t >> 6;
  const int fm = lane & 15;
  const int fg = lane >> 4;

  const int rb = t >> 3;          // staging: i-lane 0..31
  const int k4 = 4 * (t & 7);     // staging: k-quad 0,4,..28

  f32x4 accF[4][NT];
  #pragma unroll
  for (int mt = 0; mt < 4; ++mt)
    #pragma unroll
    for (int nt = 0; nt < NT; ++nt) accF[mt][nt] = (f32x4){0.f, 0.f, 0.f, 0.f};
  float rs[4] = {0.f, 0.f, 0.f, 0.f};

  float4 aR0, aR1, aR2, aR3;      // staged adj chunk (next to write)
  #define LOADCH(kb_) do { \
    aR0 = *(const float4*)&adj[(size_t)(I0 +   0 + rb) * NROW + (kb_) + k4]; \
    aR1 = *(const float4*)&adj[(size_t)(I0 +  32 + rb) * NROW + (kb_) + k4]; \
    aR2 = *(const float4*)&adj[(size_t)(I0 +  64 + rb) * NROW + (kb_) + k4]; \
    aR3 = *(const float4*)&adj[(size_t)(I0 +  96 + rb) * NROW + (kb_) + k4]; \
  } while (0)
  #define WRITECH(buf) do { \
    const float4 ar_[4] = {aR0, aR1, aR2, aR3}; \
    _Pragma("unroll") \
    for (int q = 0; q < 4; ++q) { \
      const int i_ = q * 32 + rb; \
      const float vv_[4] = {ar_[q].x, ar_[q].y, ar_[q].z, ar_[q].w}; \
      _Pragma("unroll") \
      for (int j = 0; j < 4; ++j) aP[buf][(k4 + j) * 132 + i_] = packHL(vv_[j]); \
    } \
  } while (0)

  // prologue: chunk 0 staged into aP[0]; chunk 1 loads in flight
  LOADCH(K0);
  WRITECH(0);
  LOADCH(K0 + 32);
  bar_lds();

  for (int ch = 0; ch < 16; ++ch) {
    const int cur = ch & 1;
    const int kb = K0 + ch * 32;
    // ---- compute chunk ch ----
    if (wid < 2) {
      // fwd: A from global f32 (L2-hot) + cvt; B from XT global
      s16x8 bh[NT], bl[NT];
      #pragma unroll
      for (int nt = 0; nt < NT; ++nt)
        ldXT8(&XT[(size_t)(nt * 16 + fm) * NROW + kb + 8 * fg], bh[nt], bl[nt]);
      #pragma unroll
      for (int mt = 0; mt < 4; ++mt) {
        const int row = I0 + (wid * 4 + mt) * 16 + fm;
        float av[8];
        ld8(&adj[(size_t)row * NROW + kb + 8 * fg], av);
        s16x8 ah, al;
        cvt_hilo8(av, ah, al);
        if (SUMS) {
          #pragma unroll
          for (int j = 0; j < 8; ++j) rs[mt] += fabsf(av[j]);
        }
        #pragma unroll
        for (int nt = 0; nt < NT; ++nt) {
          accF[mt][nt] = __builtin_amdgcn_mfma_f32_16x16x32_bf16(ah, bh[nt], accF[mt][nt], 0, 0, 0);
          accF[mt][nt] = __builtin_amdgcn_mfma_f32_16x16x32_bf16(ah, bl[nt], accF[mt][nt], 0, 0, 0);
          accF[mt][nt] = __builtin_amdgcn_mfma_f32_16x16x32_bf16(al, bh[nt], accF[mt][nt], 0, 0, 0);
        }
      }
    } else {
      // tr: A from aP[cur] (uint4 b128 reads); B from XT global
      const int kt = wid - 2;
      f32x4 accT[NT];
      #pragma unroll
      for (int ct = 0; ct < NT; ++ct) accT[ct] = (f32x4){0.f, 0.f, 0.f, 0.f};
      float cs = 0.f;
      #pragma unroll
      for (int iw = 0; iw < 4; ++iw) {
        const uint32_t* ap = &aP[cur][(kt * 16 + fm) * 132 + iw * 32 + 8 * fg];
        const uint4 ua = *(const uint4*)ap;
        const uint4 ub = *(const uint4*)(ap + 4);
        const uint32_t u[8] = {ua.x, ua.y, ua.z, ua.w, ub.x, ub.y, ub.z, ub.w};
        s16x8 ah, al;
        unpack8(u, ah, al);
        if (SUMS) {
          #pragma unroll
          for (int j = 0; j < 8; ++j) cs += fabsf(bf2f(ah[j]) + bf2f(al[j]));
        }
        #pragma unroll
        for (int ct = 0; ct < NT; ++ct) {
          s16x8 xh, xl;
          ldXT8(&XT[(size_t)(ct * 16 + fm) * NROW + I0 + iw * 32 + 8 * fg], xh, xl);
          accT[ct] = __builtin_amdgcn_mfma_f32_16x16x32_bf16(ah, xh, accT[ct], 0, 0, 0);
          accT[ct] = __builtin_amdgcn_mfma_f32_16x16x32_bf16(ah, xl, accT[ct], 0, 0, 0);
          accT[ct] = __builtin_amdgcn_mfma_f32_16x16x32_bf16(al, xh, accT[ct], 0, 0, 0);
        }
      }
      #pragma unroll
      for (int ct = 0; ct < NT; ++ct)
        #pragma unroll
        for (int r = 0; r < 4; ++r)
          Gp[((size_t)iz * NROW + kb + kt * 16 + 4 * fg + r) * 32 + ct * 16 + fm] = accT[ct][r];
      if (SUMS) {
        cs += __shfl_xor(cs, 16, 64);
        cs += __shfl_xor(cs, 32, 64);
        if (lane < 16) csP[(size_t)iz * NROW + kb + kt * 16 + lane] = cs;
      }
    }
    // ---- stage chunk ch+1 into aP[cur^1]; issue loads for ch+2 ----
    if (ch < 15) WRITECH(cur ^ 1);
    if (ch < 14) LOADCH(kb + 64);
    bar_lds();
  }
  #undef LOADCH
  #undef WRITECH

  // ---- fwd epilogue: write Fp (+rsP) ----
  if (wid < 2) {
    #pragma unroll
    for (int mt = 0; mt < 4; ++mt) {
      const int rowb = I0 + (wid * 4 + mt) * 16;
      #pragma unroll
      for (int nt = 0; nt < NT; ++nt)
        #pragma unroll
        for (int r = 0; r < 4; ++r)
          Fp[((size_t)kz * NROW + rowb + 4 * fg + r) * 32 + nt * 16 + fm] = accF[mt][nt][r];
      if (SUMS) {
        float v = rs[mt];
        v += __shfl_xor(v, 16, 64);
        v += __shfl_xor(v, 32, 64);
        if (lane < 16) rsP[(size_t)kz * NROW + rowb + lane] = v;
      }
    }
  }
}

// ---------------- S1: fold pass1 (f64), build l1, v1 (+XT2), mean-l1 partials ----------------
// grid 256 (32 rows/block), block 256
__global__ __launch_bounds__(256) void k_s1(const float* __restrict__ Fp, const float* __restrict__ rsP,
                                            const float* __restrict__ Gp, const float* __restrict__ csP,
                                            const float* __restrict__ x,  const float* __restrict__ W1,
                                            const float* __restrict__ b1,
                                            float* __restrict__ rowsum, float* __restrict__ colsum,
                                            float* __restrict__ v1, uint32_t* __restrict__ XT2,
                                            float* __restrict__ mlp) {
  __shared__ float l1L[32 * 100];
  __shared__ float rsL[32], csL[32];
  const int t = threadIdx.x;
  const int n0 = blockIdx.x * 32;
  if (t < 32) {
    double s = 0.;
    for (int p = 0; p < 16; ++p) s += (double)rsP[(size_t)p * NROW + n0 + t];
    s = fmax(s, 1e-12);
    rowsum[n0 + t] = (float)s; rsL[t] = (float)s;
  } else if (t < 64) {
    const int r = t - 32;
    double s = 0.;
    for (int p = 0; p < 64; ++p) s += (double)csP[(size_t)p * NROW + n0 + r];
    s = fmax(s, 1e-12);
    colsum[n0 + r] = (float)s; csL[r] = (float)s;
  }
  __syncthreads();
  {
    const int r = t >> 3, c = (t & 7) * 4;
    const int n = n0 + r;
    double s[4] = {0., 0., 0., 0.};
    for (int p = 0; p < 16; ++p) {
      const float4 v = *(const float4*)&Fp[((size_t)p * NROW + n) * 32 + c];
      s[0] += v.x; s[1] += v.y; s[2] += v.z; s[3] += v.w;
    }
    const double rsv = (double)rsL[r];
    #pragma unroll
    for (int q = 0; q < 4; ++q) l1L[r * 100 + c + q] = (float)(s[q] / rsv);
    double sg[4] = {0., 0., 0., 0.};
    for (int p = 0; p < 64; ++p) {
      const float4 v = *(const float4*)&Gp[((size_t)p * NROW + n) * 32 + c];
      sg[0] += v.x; sg[1] += v.y; sg[2] += v.z; sg[3] += v.w;
    }
    const double csv = (double)csL[r];
    #pragma unroll
    for (int q = 0; q < 4; ++q) l1L[r * 100 + 32 + c + q] = (float)(sg[q] / csv);
    *(float4*)&l1L[r * 100 + 64 + c] = *(const float4*)&x[(size_t)n * 32 + c];
  }
  __syncthreads();
  if (t < 96) {
    double s = 0.;
    for (int r = 0; r < 32; ++r) s += (double)l1L[r * 100 + t];
    mlp[(size_t)blockIdx.x * 96 + t] = (float)s;
  }
  {
    const int r = t & 31, jg = t >> 5;
    const int n = n0 + r;
    float accv[4];
    #pragma unroll
    for (int jj = 0; jj < 4; ++jj) accv[jj] = b1[4 * jg + jj];
    for (int k = 0; k < 96; k += 4) {
      const float4 lv = *(const float4*)&l1L[r * 100 + k];
      #pragma unroll
      for (int jj = 0; jj < 4; ++jj) {
        const float4 wv = *(const float4*)&W1[(size_t)(4 * jg + jj) * 96 + k];
        accv[jj] += lv.x * wv.x + lv.y * wv.y + lv.z * wv.z + lv.w * wv.w;
      }
    }
    #pragma unroll
    for (int jj = 0; jj < 4; ++jj) {
      const float o = leaky(accv[jj]);
      v1[(size_t)n * 32 + 4 * jg + jj] = o;
      XT2[(size_t)(4 * jg + jj) * NROW + n] = packHL(o);
    }
  }
}

// ---------------- S2: u1 (f64 folds) ----------------
__global__ void k_s2(const float* __restrict__ mlp, const float* __restrict__ uW1,
                     const float* __restrict__ ub1, float* __restrict__ u1) {
  __shared__ float ml[96];
  const int t = threadIdx.x;  // block 128
  if (t < 96) {
    double s = 0.;
    for (int b = 0; b < 256; ++b) s += (double)mlp[(size_t)b * 96 + t];
    ml[t] = (float)(s * (1.0 / 8192.0));
  }
  __syncthreads();
  if (t < 16) {
    double a = (double)ub1[t];
    for (int k = 0; k < 96; ++k) a += (double)ml[k] * (double)uW1[(size_t)t * 96 + k];
    u1[t] = (float)leakyd(a);
  }
}

// ---------------- S4: fold pass2 -> vec LDS; per-thread one gate row; LSTM combine ----------------
// grid 512 (16 rows/block), block 256
__global__ __launch_bounds__(256) void k_s4(const float* __restrict__ Fp, const float* __restrict__ Gp,
                                            const float* __restrict__ v1, const float* __restrict__ u1,
                                            const float* __restrict__ rowsum, const float* __restrict__ colsum,
                                            const float* __restrict__ Wih, const float* __restrict__ Whh,
                                            const float* __restrict__ bih, const float* __restrict__ bhh,
                                            const float* __restrict__ h_in, const float* __restrict__ c_in,
                                            float* __restrict__ out, float* __restrict__ v2,
                                            uint32_t* __restrict__ XT3, float* __restrict__ u2p) {
  __shared__ float vecL[16 * 148];    // [u1(16) | Av1(32) | ATv1(32) | v1(32) | h(32)] per row
  __shared__ float gL[16 * 132];      // gates [row][128] (+4 pad)
  __shared__ float rsL[16], csL[16];
  __shared__ float hoL[16 * 17];      // h_out cols 16..31
  const int t = threadIdx.x;
  const int n0 = blockIdx.x * 16;
  if (t < 16) rsL[t] = rowsum[n0 + t];
  else if (t < 32) csL[t - 16] = colsum[n0 + t - 16];
  { const int r = t >> 4, k = t & 15; vecL[r * 148 + k] = u1[k]; }
  __syncthreads();
  // ---- Phase A: fold split-K partials into vec ----
  {
    const int r = t >> 4, q = t & 15;
    const int n = n0 + r;
    if (q < 8) {
      const int c = q * 4;
      float4 s = {0.f, 0.f, 0.f, 0.f};
      for (int p = 0; p < 16; ++p) {
        const float4 v = *(const float4*)&Fp[((size_t)p * NROW + n) * 32 + c];
        s.x += v.x; s.y += v.y; s.z += v.z; s.w += v.w;
      }
      const float rsv = rsL[r];
      float4 o = {s.x / rsv, s.y / rsv, s.z / rsv, s.w / rsv};
      *(float4*)&vecL[r * 148 + 16 + c] = o;
      *(float4*)&vecL[r * 148 + 80 + c] = *(const float4*)&v1[(size_t)n * 32 + c];
    } else {
      const int c = (q - 8) * 4;
      float4 s = {0.f, 0.f, 0.f, 0.f};
      for (int p = 0; p < 64; ++p) {
        const float4 v = *(const float4*)&Gp[((size_t)p * NROW + n) * 32 + c];
        s.x += v.x; s.y += v.y; s.z += v.z; s.w += v.w;
      }
      const float csv = csL[r];
      float4 o = {s.x / csv, s.y / csv, s.z / csv, s.w / csv};
      *(float4*)&vecL[r * 148 + 48 + c] = o;
      *(float4*)&vecL[r * 148 + 112 + c] = *(const float4*)&h_in[(size_t)n * 32 + c];
    }
  }
  __syncthreads();
  // ---- Phase B: gates. gate = t&127, 8 rows each ----
  {
    const int gate = t & 127;
    const int half = t >> 7;
    const float bias = bih[gate] + bhh[gate];
    float acc[8];
    #pragma unroll
    for (int rr = 0; rr < 8; ++rr) acc[rr] = bias;
    const float* __restrict__ Wrow = Wih + (size_t)gate * 112;
    const float* __restrict__ vbase = vecL + (half * 8) * 148;
    #pragma unroll 4
    for (int kq = 0; kq < 28; ++kq) {
      const float4 w = *(const float4*)&Wrow[kq * 4];
      #pragma unroll
      for (int rr = 0; rr < 8; ++rr) {
        const float4 v = *(const float4*)&vbase[rr * 148 + kq * 4];
        acc[rr] += w.x * v.x + w.y * v.y + w.z * v.z + w.w * v.w;
      }
    }
    const float* __restrict__ Hrow = Whh + (size_t)gate * 32;
    #pragma unroll 4
    for (int kq = 0; kq < 8; ++kq) {
      const float4 w = *(const float4*)&Hrow[kq * 4];
      #pragma unroll
      for (int rr = 0; rr < 8; ++rr) {
        const float4 v = *(const float4*)&vbase[rr * 148 + 112 + kq * 4];
        acc[rr] += w.x * v.x + w.y * v.y + w.z * v.z + w.w * v.w;
      }
    }
    #pragma unroll
    for (int rr = 0; rr < 8; ++rr) gL[(half * 8 + rr) * 132 + gate] = acc[rr];
  }
  __syncthreads();
  // ---- Phase C: LSTM combine, outputs ----
  #pragma unroll
  for (int it = 0; it < 2; ++it) {
    const int w = it * 256 + t;
    const int r = w >> 5, j = w & 31;
    const int n = n0 + r;
    const float iv = gL[r * 132 + j];
    const float fv = gL[r * 132 + 32 + j];
    const float gv = gL[r * 132 + 64 + j];
    const float ov = gL[r * 132 + 96 + j];
    const float cv = c_in[(size_t)n * 32 + j];
    const float cn = sigf(fv) * cv + sigf(iv) * tanhf(gv);
    const float hn = sigf(ov) * tanhf(cn);
    out[8192 + (size_t)n * 32 + j] = hn;
    out[8192 + 262144 + (size_t)n * 32 + j] = cn;
    if (j < 16) {
      const float o = leaky(hn);
      v2[(size_t)n * 16 + j] = o;
      XT3[(size_t)j * NROW + n] = packHL(o);
    } else {
      hoL[r * 17 + (j - 16)] = hn;
    }
  }
  __syncthreads();
  if (t < 16) {
    float s = 0.f;
    for (int r2 = 0; r2 < 16; ++r2) s += hoL[r2 * 17 + t];
    u2p[(size_t)blockIdx.x * 16 + t] = s;
  }
}

// ---------------- S5: u2 (f64 fold) ----------------
__global__ void k_s5(const float* __restrict__ u2p, float* __restrict__ u2) {
  const int t = threadIdx.x;  // block 64
  if (t < 16) {
    double s = 0.;
    for (int b = 0; b < 512; ++b) s += (double)u2p[(size_t)b * 16 + t];
    u2[t] = (float)leakyd(s * (1.0 / 8192.0));
  }
}

// ---------------- S6: fold pass3 (f64), layer3 (f64), logits, gumbel-argmax ----------------
// grid 128 (64 rows/block), block 256
// RNG: JAX partitionable threefry: (o0,o1)=threefry2x32(key,(0,m)); bits = o0^o1. VERIFIED r4.
__global__ __launch_bounds__(256) void k_s6(const float* __restrict__ Fp, const float* __restrict__ Gp,
                                            const float* __restrict__ v2, const float* __restrict__ u2,
                                            const float* __restrict__ rowsum, const float* __restrict__ colsum,
                                            const float* __restrict__ W3, const float* __restrict__ b3,
                                            float* __restrict__ out) {
  __shared__ float l3L[64 * 68];
  __shared__ float w3L[192];
  __shared__ float b3L[3];
  __shared__ double lgL[64 * 4];
  __shared__ float rsL[64], csL[64];
  const int t = threadIdx.x;
  const int n0 = blockIdx.x * 64;
  if (t < 192) w3L[t] = W3[t];
  if (t < 3) b3L[t] = b3[t];
  if (t < 64) rsL[t] = rowsum[n0 + t];
  else if (t < 128) csL[t - 64] = colsum[n0 + t - 64];
  __syncthreads();
  {
    const int r = t >> 2, q = t & 3;
    const int n = n0 + r;
    if (q == 0) {
      #pragma unroll
      for (int cc = 0; cc < 4; ++cc) *(float4*)&l3L[r * 68 + cc * 4] = *(const float4*)&u2[cc * 4];
    } else if (q == 1) {
      const double rsv = (double)rsL[r];
      #pragma unroll
      for (int cc = 0; cc < 4; ++cc) {
        const int c = cc * 4;
        double s[4] = {0., 0., 0., 0.};
        for (int p = 0; p < 16; ++p) {
          const float4 v = *(const float4*)&Fp[((size_t)p * NROW + n) * 32 + c];
          s[0] += v.x; s[1] += v.y; s[2] += v.z; s[3] += v.w;
        }
        #pragma unroll
        for (int q2 = 0; q2 < 4; ++q2) l3L[r * 68 + 16 + c + q2] = (float)(s[q2] / rsv);
      }
    } else if (q == 2) {
      const double csv = (double)csL[r];
      #pragma unroll
      for (int cc = 0; cc < 4; ++cc) {
        const int c = cc * 4;
        double s[4] = {0., 0., 0., 0.};
        for (int p = 0; p < 64; ++p) {
          const float4 v = *(const float4*)&Gp[((size_t)p * NROW + n) * 32 + c];
          s[0] += v.x; s[1] += v.y; s[2] += v.z; s[3] += v.w;
        }
        #pragma unroll
        for (int q2 = 0; q2 < 4; ++q2) l3L[r * 68 + 32 + c + q2] = (float)(s[q2] / csv);
      }
    } else {
      #pragma unroll
      for (int cc = 0; cc < 4; ++cc)
        *(float4*)&l3L[r * 68 + 48 + cc * 4] = *(const float4*)&v2[(size_t)n * 16 + cc * 4];
    }
  }
  __syncthreads();
  {
    const int r = t >> 2, q = t & 3;
    if (q < 3) {
      double a = (double)b3L[q];
      for (int k = 0; k < 64; ++k) a += (double)l3L[r * 68 + k] * (double)w3L[q * 64 + k];
      lgL[r * 4 + q] = 2.0 * tanh(a);
    }
  }
  __syncthreads();
  if ((t & 3) == 0) {
    const int r = t >> 2;
    const int n = n0 + r;
    int best = 0;
    double bv = -1.0e300;
    #pragma unroll
    for (int j = 0; j < 3; ++j) {
      const uint32_t m = (uint32_t)(n * 3 + j);
      uint32_t o0, o1;
      threefry(0u, m, o0, o1);           // partitionable: counter64 = m -> (hi=0, lo=m)
      const uint32_t bits = o0 ^ o1;     // 32-bit output word
      const float f = __uint_as_float((bits >> 9) | 0x3f800000u) - 1.0f;
      const double u = fmax((double)f, 1.17549435e-38);
      const double g = -log(-log(u));
      const double val = g + lgL[r * 4 + j];
      if (val > bv) { bv = val; best = j; }
    }
    out[n] = (float)best - 1.0f;
  }
}

// ---------------- launch ----------------
extern "C" void kernel_launch(void* const* d_in, const int* in_sizes, int n_in,
                              void* d_out, int out_size, void* d_ws, size_t ws_size,
                              hipStream_t stream) {
  const float* adj = (const float*)d_in[0];
  const float* x   = (const float*)d_in[1];
  const float* h   = (const float*)d_in[2];
  const float* c   = (const float*)d_in[3];
  const float* W1  = (const float*)d_in[4];
  const float* b1  = (const float*)d_in[5];
  const float* uW1 = (const float*)d_in[6];
  const float* ub1 = (const float*)d_in[7];
  const float* Wih = (const float*)d_in[8];
  const float* Whh = (const float*)d_in[9];
  const float* bih = (const float*)d_in[10];
  const float* bhh = (const float*)d_in[11];
  const float* W3  = (const float*)d_in[12];
  const float* b3  = (const float*)d_in[13];
  float* out = (float*)d_out;
  float* ws  = (float*)d_ws;

  float* Fp  = ws + W_FP;
  float* Gp  = ws + W_GP;
  float* rsP = ws + W_RSP;
  float* csP = ws + W_CSP;
  float* rs  = ws + W_RS;
  float* cs  = ws + W_CS;
  float* v1  = ws + W_V1;
  float* v2  = ws + W_V2;
  float* u1  = ws + W_U1;
  float* u2  = ws + W_U2;
  float* mlp = ws + W_MLP;
  float* u2p = ws + W_U2P;
  uint32_t* XT1 = (uint32_t*)(ws + W_XT1);
  uint32_t* XT2 = (uint32_t*)(ws + W_XT2);
  uint32_t* XT3 = (uint32_t*)(ws + W_XT3);

  // ---- pass 1: adj @ x AND adj.T @ x (+ row/col sums) ----
  k_xt<32><<<32, 256, 0, stream>>>(x, XT1);
  k_gemm<32, true><<<dim3(64, 16), 256, 0, stream>>>(adj, XT1, Fp, Gp, rsP, csP);
  k_s1<<<256, 256, 0, stream>>>(Fp, rsP, Gp, csP, x, W1, b1, rs, cs, v1, XT2, mlp);
  k_s2<<<1, 128, 0, stream>>>(mlp, uW1, ub1, u1);

  // ---- pass 2: adj @ v1 AND adj.T @ v1 ; LSTM ----
  k_gemm<32, false><<<dim3(64, 16), 256, 0, stream>>>(adj, XT2, Fp, Gp, nullptr, nullptr);
  k_s4<<<512, 256, 0, stream>>>(Fp, Gp, v1, u1, rs, cs, Wih, Whh, bih, bhh, h, c, out, v2, XT3, u2p);
  k_s5<<<1, 64, 0, stream>>>(u2p, u2);

  // ---- pass 3: adj @ v2 AND adj.T @ v2 ; layer3 + sampling ----
  k_gemm<16, false><<<dim3(64, 16), 256, 0, stream>>>(adj, XT3, Fp, Gp, nullptr, nullptr);
  k_s6<<<128, 256, 0, stream>>>(Fp, Gp, v2, u2, rs, cs, W3, b3, out);
}

// Round 15
// 426.883 us; speedup vs baseline: 1.4100x; 1.4100x over previous
//
#include <hip/hip_runtime.h>
#include <stdint.h>
#include <math.h>

#define NROW 8192
// dims: IN=32, G=16, H1=32, H2=16, LSTM_HID = 32
// out: actions[8192], h_out @ 8192, c_out @ 270336

// ---------------- workspace layout (floats, in d_ws; ws_size = 1 GiB) ----------------
constexpr size_t W_FP  = 0;                              // fwd partials [32][8192][32]
constexpr size_t W_GP  = W_FP  + (size_t)32*NROW*32;     // tr  partials [64][8192][32]
constexpr size_t W_RSP = W_GP  + (size_t)64*NROW*32;     // rowsum partials [32][8192]
constexpr size_t W_CSP = W_RSP + (size_t)32*NROW;        // colsum partials [64][8192]
constexpr size_t W_RS  = W_CSP + (size_t)64*NROW;        // rowsum [8192]
constexpr size_t W_CS  = W_RS  + NROW;                   // colsum [8192]
constexpr size_t W_V1  = W_CS  + NROW;                   // v1 [8192][32]
constexpr size_t W_V2  = W_V1  + (size_t)NROW*32;        // v2 [8192][16]
constexpr size_t W_U1  = W_V2  + (size_t)NROW*16;        // u1 [16]
constexpr size_t W_U2  = W_U1  + 16;                     // u2 [16]
constexpr size_t W_MLP = W_U2  + 16;                     // l1-mean partials [256][96]
constexpr size_t W_U2P = W_MLP + (size_t)256*96;         // u2 partials [512][16]
// total ~26.4M floats = 106 MB << 1 GiB

typedef float f32x4 __attribute__((ext_vector_type(4)));
typedef short s16x8 __attribute__((ext_vector_type(8)));

__device__ __forceinline__ float leaky(float v) { return v >= 0.f ? v : 0.01f * v; }
__device__ __forceinline__ float sigf(float v) { return 1.f / (1.f + __expf(-v)); }
__device__ __forceinline__ double leakyd(double v) { return v >= 0. ? v : 0.01 * v; }

// f32 -> bf16 (RNE)
__device__ __forceinline__ uint32_t bf16rne(float x) {
  uint32_t b = __float_as_uint(x);
  return (b + 0x7FFFu + ((b >> 16) & 1u)) >> 16;
}
__device__ __forceinline__ float bf2f(short s) {
  return __uint_as_float(((uint32_t)(uint16_t)s) << 16);
}
// pack f32 -> (hi bf16) | (lo bf16 << 16)
__device__ __forceinline__ uint32_t packHL(float x) {
  const uint32_t hb = bf16rne(x);
  const float hf = __uint_as_float(hb << 16);
  const uint32_t lb = bf16rne(x - hf);
  return hb | (lb << 16);
}
__device__ __forceinline__ void cvt_hilo8(const float v[8], s16x8& h, s16x8& l) {
  #pragma unroll
  for (int j = 0; j < 8; ++j) {
    const uint32_t hb = bf16rne(v[j]);
    const float hf = __uint_as_float(hb << 16);
    h[j] = (short)hb;
    l[j] = (short)bf16rne(v[j] - hf);
  }
}
__device__ __forceinline__ void unpack8(const uint32_t u[8], s16x8& h, s16x8& l) {
  #pragma unroll
  for (int j = 0; j < 8; ++j) { h[j] = (short)(u[j] & 0xffffu); l[j] = (short)(u[j] >> 16); }
}
__device__ __forceinline__ void ld8(const float* p, float v[8]) {
  const float4 a = *(const float4*)p;
  const float4 b = *(const float4*)(p + 4);
  v[0]=a.x; v[1]=a.y; v[2]=a.z; v[3]=a.w; v[4]=b.x; v[5]=b.y; v[6]=b.z; v[7]=b.w;
}

// JAX threefry2x32 (20 rounds), key = (0, 42)
__device__ __forceinline__ void threefry(uint32_t x0, uint32_t x1, uint32_t& o0, uint32_t& o1) {
  const uint32_t ks0 = 0u, ks1 = 42u;
  const uint32_t ks2 = ks0 ^ ks1 ^ 0x1BD11BDAu;
  uint32_t ks[3] = {ks0, ks1, ks2};
  const int R0[4] = {13, 15, 26, 6};
  const int R1[4] = {17, 29, 16, 24};
  x0 += ks[0]; x1 += ks[1];
  #pragma unroll
  for (int g = 0; g < 5; ++g) {
    const int* R = (g & 1) ? R1 : R0;
    #pragma unroll
    for (int i = 0; i < 4; ++i) {
      x0 += x1;
      x1 = (x1 << R[i]) | (x1 >> (32 - R[i]));
      x1 ^= x0;
    }
    x0 += ks[(g + 1) % 3];
    x1 += ks[(g + 2) % 3] + (uint32_t)(g + 1);
  }
  o0 = x0; o1 = x1;
}

// ---------------- fused MFMA GEMM (r9 structure, finer split-K): Fp[kz]=adj@X, Gp[iz]=adj^T@X ----
// bf16 hi/lo split (3 MFMA) ~ f32 accuracy. grid (64 iz, 32 kz), block 256 = 4 waves.
// Tile 128 i x 256 k (8 chunks of 32 k). waves 0,1: fwd (A global f32+cvt; B XkH/XkL LDS);
// waves 2,3: tr (A from aP packed-u32 k-major LDS; B X2h/X2l LDS). __syncthreads barriers (r9).
template <int C, bool SUMS>
__global__ __launch_bounds__(256) void k_gemm(const float* __restrict__ adj,
                                              const float* __restrict__ X,
                                              float* __restrict__ Fp,
                                              float* __restrict__ Gp,
                                              float* __restrict__ rsP,
                                              float* __restrict__ csP) {
  constexpr int NT = C / 16;
  __shared__ alignas(16) uint32_t aP[32 * 132];  // adj chunk k-major, packed hi|lo<<16
  __shared__ alignas(16) short X2h[C * 136];     // X rows I0..I0+127 transposed, bf16 hi
  __shared__ alignas(16) short X2l[C * 136];
  __shared__ alignas(16) short XkH[C * 40];      // X chunk transposed [c][32 k], bf16 hi
  __shared__ alignas(16) short XkL[C * 40];
  const int t = threadIdx.x;
  const int iz = blockIdx.x;      // 0..63
  const int kz = blockIdx.y;      // 0..31
  const int I0 = iz * 128;
  const int K0 = kz * 256;
  const int lane = t & 63;
  const int wid = t >> 6;
  const int fm = lane & 15;
  const int fg = lane >> 4;

  // ---- stage X2 (rows I0..I0+127, transposed, bf16 hi/lo) ----
  if constexpr (C == 32) {
    #pragma unroll
    for (int r = 0; r < 4; ++r) {
      const int i = r * 32 + (t >> 3);
      const int c4 = 4 * (t & 7);
      const float4 v = *(const float4*)&X[(size_t)(I0 + i) * 32 + c4];
      const float vv[4] = {v.x, v.y, v.z, v.w};
      #pragma unroll
      for (int j = 0; j < 4; ++j) {
        const uint32_t p = packHL(vv[j]);
        X2h[(c4 + j) * 136 + i] = (short)(p & 0xffffu);
        X2l[(c4 + j) * 136 + i] = (short)(p >> 16);
      }
    }
  } else {
    if (t < 128) {
      #pragma unroll
      for (int r = 0; r < 4; ++r) {
        const int i = r * 32 + (t >> 2);
        const int c4 = 4 * (t & 3);
        const float4 v = *(const float4*)&X[(size_t)(I0 + i) * 16 + c4];
        const float vv[4] = {v.x, v.y, v.z, v.w};
        #pragma unroll
        for (int j = 0; j < 4; ++j) {
          const uint32_t p = packHL(vv[j]);
          X2h[(c4 + j) * 136 + i] = (short)(p & 0xffffu);
          X2l[(c4 + j) * 136 + i] = (short)(p >> 16);
        }
      }
    }
  }

  f32x4 accF[4][NT];
  #pragma unroll
  for (int mt = 0; mt < 4; ++mt)
    #pragma unroll
    for (int nt = 0; nt < NT; ++nt) accF[mt][nt] = (f32x4){0.f, 0.f, 0.f, 0.f};
  float rs[4] = {0.f, 0.f, 0.f, 0.f};

  const int rb = t >> 3;          // staging: i-lane 0..31
  const int k4 = 4 * (t & 7);     // staging: k-quad 0,4,..28

  for (int ch = 0; ch < 8; ++ch) {
    const int kb = K0 + ch * 32;
    __syncthreads();
    // ---- stage adj chunk -> aP (k-major packed u32) ----
    #pragma unroll
    for (int q = 0; q < 4; ++q) {
      const int i = q * 32 + rb;
      const float4 v = *(const float4*)&adj[(size_t)(I0 + i) * NROW + kb + k4];
      const float vv[4] = {v.x, v.y, v.z, v.w};
      #pragma unroll
      for (int j = 0; j < 4; ++j) aP[(k4 + j) * 132 + i] = packHL(vv[j]);
    }
    // ---- stage Xk ----
    if constexpr (C == 32) {
      const int k = t >> 3, c4 = 4 * (t & 7);
      const float4 v = *(const float4*)&X[(size_t)(kb + k) * 32 + c4];
      const float vv[4] = {v.x, v.y, v.z, v.w};
      #pragma unroll
      for (int j = 0; j < 4; ++j) {
        const uint32_t p = packHL(vv[j]);
        XkH[(c4 + j) * 40 + k] = (short)(p & 0xffffu);
        XkL[(c4 + j) * 40 + k] = (short)(p >> 16);
      }
    } else {
      if (t < 128) {
        const int k = t >> 2, c4 = 4 * (t & 3);
        const float4 v = *(const float4*)&X[(size_t)(kb + k) * 16 + c4];
        const float vv[4] = {v.x, v.y, v.z, v.w};
        #pragma unroll
        for (int j = 0; j < 4; ++j) {
          const uint32_t p = packHL(vv[j]);
          XkH[(c4 + j) * 40 + k] = (short)(p & 0xffffu);
          XkL[(c4 + j) * 40 + k] = (short)(p >> 16);
        }
      }
    }
    __syncthreads();
    if (wid < 2) {
      // ---- fwd: A from global f32 (coalesced, L2-hot) + cvt; B direct s16x8. ----
      s16x8 bh[NT], bl[NT];
      #pragma unroll
      for (int nt = 0; nt < NT; ++nt) {
        bh[nt] = *(const s16x8*)&XkH[(nt * 16 + fm) * 40 + 8 * fg];
        bl[nt] = *(const s16x8*)&XkL[(nt * 16 + fm) * 40 + 8 * fg];
      }
      #pragma unroll
      for (int mt = 0; mt < 4; ++mt) {
        const int row = I0 + (wid * 4 + mt) * 16 + fm;
        float av[8];
        ld8(&adj[(size_t)row * NROW + kb + 8 * fg], av);
        s16x8 ah, al;
        cvt_hilo8(av, ah, al);
        if (SUMS) {
          #pragma unroll
          for (int j = 0; j < 8; ++j) rs[mt] += fabsf(av[j]);
        }
        #pragma unroll
        for (int nt = 0; nt < NT; ++nt) {
          accF[mt][nt] = __builtin_amdgcn_mfma_f32_16x16x32_bf16(ah, bh[nt], accF[mt][nt], 0, 0, 0);
          accF[mt][nt] = __builtin_amdgcn_mfma_f32_16x16x32_bf16(ah, bl[nt], accF[mt][nt], 0, 0, 0);
          accF[mt][nt] = __builtin_amdgcn_mfma_f32_16x16x32_bf16(al, bh[nt], accF[mt][nt], 0, 0, 0);
        }
      }
    } else {
      // ---- tr: A-frags from aP (uint4 b128 reads + unpack). ----
      const int kt = wid - 2;
      f32x4 accT[NT];
      #pragma unroll
      for (int ct = 0; ct < NT; ++ct) accT[ct] = (f32x4){0.f, 0.f, 0.f, 0.f};
      float cs = 0.f;
      #pragma unroll
      for (int iw = 0; iw < 4; ++iw) {
        const uint32_t* ap = &aP[(kt * 16 + fm) * 132 + iw * 32 + 8 * fg];
        const uint4 ua = *(const uint4*)ap;
        const uint4 ub = *(const uint4*)(ap + 4);
        const uint32_t u[8] = {ua.x, ua.y, ua.z, ua.w, ub.x, ub.y, ub.z, ub.w};
        s16x8 ah, al;
        unpack8(u, ah, al);
        if (SUMS) {
          #pragma unroll
          for (int j = 0; j < 8; ++j) cs += fabsf(bf2f(ah[j]) + bf2f(al[j]));
        }
        #pragma unroll
        for (int ct = 0; ct < NT; ++ct) {
          const s16x8 xh = *(const s16x8*)&X2h[(ct * 16 + fm) * 136 + iw * 32 + 8 * fg];
          const s16x8 xl = *(const s16x8*)&X2l[(ct * 16 + fm) * 136 + iw * 32 + 8 * fg];
          accT[ct] = __builtin_amdgcn_mfma_f32_16x16x32_bf16(ah, xh, accT[ct], 0, 0, 0);
          accT[ct] = __builtin_amdgcn_mfma_f32_16x16x32_bf16(ah, xl, accT[ct], 0, 0, 0);
          accT[ct] = __builtin_amdgcn_mfma_f32_16x16x32_bf16(al, xh, accT[ct], 0, 0, 0);
        }
      }
      #pragma unroll
      for (int ct = 0; ct < NT; ++ct)
        #pragma unroll
        for (int r = 0; r < 4; ++r)
          Gp[((size_t)iz * NROW + kb + kt * 16 + 4 * fg + r) * 32 + ct * 16 + fm] = accT[ct][r];
      if (SUMS) {
        cs += __shfl_xor(cs, 16, 64);
        cs += __shfl_xor(cs, 32, 64);
        if (lane < 16) csP[(size_t)iz * NROW + kb + kt * 16 + lane] = cs;
      }
    }
  }
  // ---- fwd epilogue: write Fp (+rsP) ----
  if (wid < 2) {
    #pragma unroll
    for (int mt = 0; mt < 4; ++mt) {
      const int rowb = I0 + (wid * 4 + mt) * 16;
      #pragma unroll
      for (int nt = 0; nt < NT; ++nt)
        #pragma unroll
        for (int r = 0; r < 4; ++r)
          Fp[((size_t)kz * NROW + rowb + 4 * fg + r) * 32 + nt * 16 + fm] = accF[mt][nt][r];
      if (SUMS) {
        float v = rs[mt];
        v += __shfl_xor(v, 16, 64);
        v += __shfl_xor(v, 32, 64);
        if (lane < 16) rsP[(size_t)kz * NROW + rowb + lane] = v;
      }
    }
  }
}

// ---------------- S1: fold pass1 (f64), build l1, v1, mean-l1 partials ----------------
// grid 256 (32 rows/block), block 256
__global__ __launch_bounds__(256) void k_s1(const float* __restrict__ Fp, const float* __restrict__ rsP,
                                            const float* __restrict__ Gp, const float* __restrict__ csP,
                                            const float* __restrict__ x,  const float* __restrict__ W1,
                                            const float* __restrict__ b1,
                                            float* __restrict__ rowsum, float* __restrict__ colsum,
                                            float* __restrict__ v1, float* __restrict__ mlp) {
  __shared__ float l1L[32 * 100];
  __shared__ float rsL[32], csL[32];
  const int t = threadIdx.x;
  const int n0 = blockIdx.x * 32;
  if (t < 32) {
    double s = 0.;
    for (int p = 0; p < 32; ++p) s += (double)rsP[(size_t)p * NROW + n0 + t];
    s = fmax(s, 1e-12);
    rowsum[n0 + t] = (float)s; rsL[t] = (float)s;
  } else if (t < 64) {
    const int r = t - 32;
    double s = 0.;
    for (int p = 0; p < 64; ++p) s += (double)csP[(size_t)p * NROW + n0 + r];
    s = fmax(s, 1e-12);
    colsum[n0 + r] = (float)s; csL[r] = (float)s;
  }
  __syncthreads();
  {
    const int r = t >> 3, c = (t & 7) * 4;
    const int n = n0 + r;
    double s[4] = {0., 0., 0., 0.};
    for (int p = 0; p < 32; ++p) {
      const float4 v = *(const float4*)&Fp[((size_t)p * NROW + n) * 32 + c];
      s[0] += v.x; s[1] += v.y; s[2] += v.z; s[3] += v.w;
    }
    const double rsv = (double)rsL[r];
    #pragma unroll
    for (int q = 0; q < 4; ++q) l1L[r * 100 + c + q] = (float)(s[q] / rsv);
    double sg[4] = {0., 0., 0., 0.};
    for (int p = 0; p < 64; ++p) {
      const float4 v = *(const float4*)&Gp[((size_t)p * NROW + n) * 32 + c];
      sg[0] += v.x; sg[1] += v.y; sg[2] += v.z; sg[3] += v.w;
    }
    const double csv = (double)csL[r];
    #pragma unroll
    for (int q = 0; q < 4; ++q) l1L[r * 100 + 32 + c + q] = (float)(sg[q] / csv);
    *(float4*)&l1L[r * 100 + 64 + c] = *(const float4*)&x[(size_t)n * 32 + c];
  }
  __syncthreads();
  if (t < 96) {
    double s = 0.;
    for (int r = 0; r < 32; ++r) s += (double)l1L[r * 100 + t];
    mlp[(size_t)blockIdx.x * 96 + t] = (float)s;
  }
  {
    const int r = t & 31, jg = t >> 5;
    const int n = n0 + r;
    float accv[4];
    #pragma unroll
    for (int jj = 0; jj < 4; ++jj) accv[jj] = b1[4 * jg + jj];
    for (int k = 0; k < 96; k += 4) {
      const float4 lv = *(const float4*)&l1L[r * 100 + k];
      #pragma unroll
      for (int jj = 0; jj < 4; ++jj) {
        const float4 wv = *(const float4*)&W1[(size_t)(4 * jg + jj) * 96 + k];
        accv[jj] += lv.x * wv.x + lv.y * wv.y + lv.z * wv.z + lv.w * wv.w;
      }
    }
    #pragma unroll
    for (int jj = 0; jj < 4; ++jj) v1[(size_t)n * 32 + 4 * jg + jj] = leaky(accv[jj]);
  }
}

// ---------------- S2: u1 (f64 folds) ----------------
__global__ void k_s2(const float* __restrict__ mlp, const float* __restrict__ uW1,
                     const float* __restrict__ ub1, float* __restrict__ u1) {
  __shared__ float ml[96];
  const int t = threadIdx.x;  // block 128
  if (t < 96) {
    double s = 0.;
    for (int b = 0; b < 256; ++b) s += (double)mlp[(size_t)b * 96 + t];
    ml[t] = (float)(s * (1.0 / 8192.0));
  }
  __syncthreads();
  if (t < 16) {
    double a = (double)ub1[t];
    for (int k = 0; k < 96; ++k) a += (double)ml[k] * (double)uW1[(size_t)t * 96 + k];
    u1[t] = (float)leakyd(a);
  }
}

// ---------------- S4: fold pass2 -> vec LDS; per-thread one gate row; LSTM combine ----------------
// grid 512 (16 rows/block), block 256
__global__ __launch_bounds__(256) void k_s4(const float* __restrict__ Fp, const float* __restrict__ Gp,
                                            const float* __restrict__ v1, const float* __restrict__ u1,
                                            const float* __restrict__ rowsum, const float* __restrict__ colsum,
                                            const float* __restrict__ Wih, const float* __restrict__ Whh,
                                            const float* __restrict__ bih, const float* __restrict__ bhh,
                                            const float* __restrict__ h_in, const float* __restrict__ c_in,
                                            float* __restrict__ out, float* __restrict__ v2,
                                            float* __restrict__ u2p) {
  __shared__ float vecL[16 * 148];    // [u1(16) | Av1(32) | ATv1(32) | v1(32) | h(32)] per row
  __shared__ float gL[16 * 132];      // gates [row][128] (+4 pad)
  __shared__ float rsL[16], csL[16];
  __shared__ float hoL[16 * 17];      // h_out cols 16..31
  const int t = threadIdx.x;
  const int n0 = blockIdx.x * 16;
  if (t < 16) rsL[t] = rowsum[n0 + t];
  else if (t < 32) csL[t - 16] = colsum[n0 + t - 16];
  { const int r = t >> 4, k = t & 15; vecL[r * 148 + k] = u1[k]; }
  __syncthreads();
  // ---- Phase A: fold split-K partials into vec ----
  {
    const int r = t >> 4, q = t & 15;
    const int n = n0 + r;
    if (q < 8) {
      const int c = q * 4;
      float4 s = {0.f, 0.f, 0.f, 0.f};
      for (int p = 0; p < 32; ++p) {
        const float4 v = *(const float4*)&Fp[((size_t)p * NROW + n) * 32 + c];
        s.x += v.x; s.y += v.y; s.z += v.z; s.w += v.w;
      }
      const float rsv = rsL[r];
      float4 o = {s.x / rsv, s.y / rsv, s.z / rsv, s.w / rsv};
      *(float4*)&vecL[r * 148 + 16 + c] = o;
      *(float4*)&vecL[r * 148 + 80 + c] = *(const float4*)&v1[(size_t)n * 32 + c];
    } else {
      const int c = (q - 8) * 4;
      float4 s = {0.f, 0.f, 0.f, 0.f};
      for (int p = 0; p < 64; ++p) {
        const float4 v = *(const float4*)&Gp[((size_t)p * NROW + n) * 32 + c];
        s.x += v.x; s.y += v.y; s.z += v.z; s.w += v.w;
      }
      const float csv = csL[r];
      float4 o = {s.x / csv, s.y / csv, s.z / csv, s.w / csv};
      *(float4*)&vecL[r * 148 + 48 + c] = o;
      *(float4*)&vecL[r * 148 + 112 + c] = *(const float4*)&h_in[(size_t)n * 32 + c];
    }
  }
  __syncthreads();
  // ---- Phase B: gates. gate = t&127, 8 rows each ----
  {
    const int gate = t & 127;
    const int half = t >> 7;
    const float bias = bih[gate] + bhh[gate];
    float acc[8];
    #pragma unroll
    for (int rr = 0; rr < 8; ++rr) acc[rr] = bias;
    const float* __restrict__ Wrow = Wih + (size_t)gate * 112;
    const float* __restrict__ vbase = vecL + (half * 8) * 148;
    #pragma unroll 4
    for (int kq = 0; kq < 28; ++kq) {
      const float4 w = *(const float4*)&Wrow[kq * 4];
      #pragma unroll
      for (int rr = 0; rr < 8; ++rr) {
        const float4 v = *(const float4*)&vbase[rr * 148 + kq * 4];
        acc[rr] += w.x * v.x + w.y * v.y + w.z * v.z + w.w * v.w;
      }
    }
    const float* __restrict__ Hrow = Whh + (size_t)gate * 32;
    #pragma unroll 4
    for (int kq = 0; kq < 8; ++kq) {
      const float4 w = *(const float4*)&Hrow[kq * 4];
      #pragma unroll
      for (int rr = 0; rr < 8; ++rr) {
        const float4 v = *(const float4*)&vbase[rr * 148 + 112 + kq * 4];
        acc[rr] += w.x * v.x + w.y * v.y + w.z * v.z + w.w * v.w;
      }
    }
    #pragma unroll
    for (int rr = 0; rr < 8; ++rr) gL[(half * 8 + rr) * 132 + gate] = acc[rr];
  }
  __syncthreads();
  // ---- Phase C: LSTM combine, outputs ----
  #pragma unroll
  for (int it = 0; it < 2; ++it) {
    const int w = it * 256 + t;
    const int r = w >> 5, j = w & 31;
    const int n = n0 + r;
    const float iv = gL[r * 132 + j];
    const float fv = gL[r * 132 + 32 + j];
    const float gv = gL[r * 132 + 64 + j];
    const float ov = gL[r * 132 + 96 + j];
    const float cv = c_in[(size_t)n * 32 + j];
    const float cn = sigf(fv) * cv + sigf(iv) * tanhf(gv);
    const float hn = sigf(ov) * tanhf(cn);
    out[8192 + (size_t)n * 32 + j] = hn;
    out[8192 + 262144 + (size_t)n * 32 + j] = cn;
    if (j < 16) v2[(size_t)n * 16 + j] = leaky(hn);
    else hoL[r * 17 + (j - 16)] = hn;
  }
  __syncthreads();
  if (t < 16) {
    float s = 0.f;
    for (int r2 = 0; r2 < 16; ++r2) s += hoL[r2 * 17 + t];
    u2p[(size_t)blockIdx.x * 16 + t] = s;
  }
}

// ---------------- S5: u2 (f64 fold) ----------------
__global__ void k_s5(const float* __restrict__ u2p, float* __restrict__ u2) {
  const int t = threadIdx.x;  // block 64
  if (t < 16) {
    double s = 0.;
    for (int b = 0; b < 512; ++b) s += (double)u2p[(size_t)b * 16 + t];
    u2[t] = (float)leakyd(s * (1.0 / 8192.0));
  }
}

// ---------------- S6: fold pass3 (f64), layer3 (f64), logits, gumbel-argmax ----------------
// grid 128 (64 rows/block), block 256
// RNG: JAX partitionable threefry: (o0,o1)=threefry2x32(key,(0,m)); bits = o0^o1. VERIFIED r4.
__global__ __launch_bounds__(256) void k_s6(const float* __restrict__ Fp, const float* __restrict__ Gp,
                                            const float* __restrict__ v2, const float* __restrict__ u2,
                                            const float* __restrict__ rowsum, const float* __restrict__ colsum,
                                            const float* __restrict__ W3, const float* __restrict__ b3,
                                            float* __restrict__ out) {
  __shared__ float l3L[64 * 68];
  __shared__ float w3L[192];
  __shared__ float b3L[3];
  __shared__ double lgL[64 * 4];
  __shared__ float rsL[64], csL[64];
  const int t = threadIdx.x;
  const int n0 = blockIdx.x * 64;
  if (t < 192) w3L[t] = W3[t];
  if (t < 3) b3L[t] = b3[t];
  if (t < 64) rsL[t] = rowsum[n0 + t];
  else if (t < 128) csL[t - 64] = colsum[n0 + t - 64];
  __syncthreads();
  {
    const int r = t >> 2, q = t & 3;
    const int n = n0 + r;
    if (q == 0) {
      #pragma unroll
      for (int cc = 0; cc < 4; ++cc) *(float4*)&l3L[r * 68 + cc * 4] = *(const float4*)&u2[cc * 4];
    } else if (q == 1) {
      const double rsv = (double)rsL[r];
      #pragma unroll
      for (int cc = 0; cc < 4; ++cc) {
        const int c = cc * 4;
        double s[4] = {0., 0., 0., 0.};
        for (int p = 0; p < 32; ++p) {
          const float4 v = *(const float4*)&Fp[((size_t)p * NROW + n) * 32 + c];
          s[0] += v.x; s[1] += v.y; s[2] += v.z; s[3] += v.w;
        }
        #pragma unroll
        for (int q2 = 0; q2 < 4; ++q2) l3L[r * 68 + 16 + c + q2] = (float)(s[q2] / rsv);
      }
    } else if (q == 2) {
      const double csv = (double)csL[r];
      #pragma unroll
      for (int cc = 0; cc < 4; ++cc) {
        const int c = cc * 4;
        double s[4] = {0., 0., 0., 0.};
        for (int p = 0; p < 64; ++p) {
          const float4 v = *(const float4*)&Gp[((size_t)p * NROW + n) * 32 + c];
          s[0] += v.x; s[1] += v.y; s[2] += v.z; s[3] += v.w;
        }
        #pragma unroll
        for (int q2 = 0; q2 < 4; ++q2) l3L[r * 68 + 32 + c + q2] = (float)(s[q2] / csv);
      }
    } else {
      #pragma unroll
      for (int cc = 0; cc < 4; ++cc)
        *(float4*)&l3L[r * 68 + 48 + cc * 4] = *(const float4*)&v2[(size_t)n * 16 + cc * 4];
    }
  }
  __syncthreads();
  {
    const int r = t >> 2, q = t & 3;
    if (q < 3) {
      double a = (double)b3L[q];
      for (int k = 0; k < 64; ++k) a += (double)l3L[r * 68 + k] * (double)w3L[q * 64 + k];
      lgL[r * 4 + q] = 2.0 * tanh(a);
    }
  }
  __syncthreads();
  if ((t & 3) == 0) {
    const int r = t >> 2;
    const int n = n0 + r;
    int best = 0;
    double bv = -1.0e300;
    #pragma unroll
    for (int j = 0; j < 3; ++j) {
      const uint32_t m = (uint32_t)(n * 3 + j);
      uint32_t o0, o1;
      threefry(0u, m, o0, o1);           // partitionable: counter64 = m -> (hi=0, lo=m)
      const uint32_t bits = o0 ^ o1;     // 32-bit output word
      const float f = __uint_as_float((bits >> 9) | 0x3f800000u) - 1.0f;
      const double u = fmax((double)f, 1.17549435e-38);
      const double g = -log(-log(u));
      const double val = g + lgL[r * 4 + j];
      if (val > bv) { bv = val; best = j; }
    }
    out[n] = (float)best - 1.0f;
  }
}

// ---------------- launch ----------------
extern "C" void kernel_launch(void* const* d_in, const int* in_sizes, int n_in,
                              void* d_out, int out_size, void* d_ws, size_t ws_size,
                              hipStream_t stream) {
  const float* adj = (const float*)d_in[0];
  const float* x   = (const float*)d_in[1];
  const float* h   = (const float*)d_in[2];
  const float* c   = (const float*)d_in[3];
  const float* W1  = (const float*)d_in[4];
  const float* b1  = (const float*)d_in[5];
  const float* uW1 = (const float*)d_in[6];
  const float* ub1 = (const float*)d_in[7];
  const float* Wih = (const float*)d_in[8];
  const float* Whh = (const float*)d_in[9];
  const float* bih = (const float*)d_in[10];
  const float* bhh = (const float*)d_in[11];
  const float* W3  = (const float*)d_in[12];
  const float* b3  = (const float*)d_in[13];
  float* out = (float*)d_out;
  float* ws  = (float*)d_ws;

  float* Fp  = ws + W_FP;
  float* Gp  = ws + W_GP;
  float* rsP = ws + W_RSP;
  float* csP = ws + W_CSP;
  float* rs  = ws + W_RS;
  float* cs  = ws + W_CS;
  float* v1  = ws + W_V1;
  float* v2  = ws + W_V2;
  float* u1  = ws + W_U1;
  float* u2  = ws + W_U2;
  float* mlp = ws + W_MLP;
  float* u2p = ws + W_U2P;

  // ---- pass 1: adj @ x AND adj.T @ x (+ row/col sums) ----
  k_gemm<32, true><<<dim3(64, 32), 256, 0, stream>>>(adj, x, Fp, Gp, rsP, csP);
  k_s1<<<256, 256, 0, stream>>>(Fp, rsP, Gp, csP, x, W1, b1, rs, cs, v1, mlp);
  k_s2<<<1, 128, 0, stream>>>(mlp, uW1, ub1, u1);

  // ---- pass 2: adj @ v1 AND adj.T @ v1 ; LSTM ----
  k_gemm<32, false><<<dim3(64, 32), 256, 0, stream>>>(adj, v1, Fp, Gp, nullptr, nullptr);
  k_s4<<<512, 256, 0, stream>>>(Fp, Gp, v1, u1, rs, cs, Wih, Whh, bih, bhh, h, c, out, v2, u2p);
  k_s5<<<1, 64, 0, stream>>>(u2p, u2);

  // ---- pass 3: adj @ v2 AND adj.T @ v2 ; layer3 + sampling ----
  k_gemm<16, false><<<dim3(64, 32), 256, 0, stream>>>(adj, v2, Fp, Gp, nullptr, nullptr);
  k_s6<<<128, 256, 0, stream>>>(Fp, Gp, v2, u2, rs, cs, W3, b3, out);
}

// Round 16
// 371.854 us; speedup vs baseline: 1.6186x; 1.1480x over previous
//
#include <hip/hip_runtime.h>
#include <stdint.h>
#include <math.h>

#define NROW 8192
// dims: IN=32, G=16, H1=32, H2=16, LSTM_HID = 32
// out: actions[8192], h_out @ 8192, c_out @ 270336

// ---------------- workspace layout (floats, in d_ws; ws_size = 1 GiB) ----------------
constexpr size_t W_FP  = 0;                              // fwd partials [32][8192][32]
constexpr size_t W_GP  = W_FP  + (size_t)32*NROW*32;     // tr  partials [64][8192][32]
constexpr size_t W_RSP = W_GP  + (size_t)64*NROW*32;     // rowsum partials [32][8192]
constexpr size_t W_CSP = W_RSP + (size_t)32*NROW;        // colsum partials [64][8192]
constexpr size_t W_RS  = W_CSP + (size_t)64*NROW;        // rowsum [8192]
constexpr size_t W_CS  = W_RS  + NROW;                   // colsum [8192]
constexpr size_t W_V1  = W_CS  + NROW;                   // v1 [8192][32]
constexpr size_t W_V2  = W_V1  + (size_t)NROW*32;        // v2 [8192][16]
constexpr size_t W_U1  = W_V2  + (size_t)NROW*16;        // u1 [16]
constexpr size_t W_U2  = W_U1  + 16;                     // u2 [16]
constexpr size_t W_MLP = W_U2  + 16;                     // l1-mean partials [256][96]
constexpr size_t W_U2P = W_MLP + (size_t)256*96;         // u2 partials [512][16]

typedef float f32x4 __attribute__((ext_vector_type(4)));
typedef short s16x8 __attribute__((ext_vector_type(8)));

__device__ __forceinline__ float leaky(float v) { return v >= 0.f ? v : 0.01f * v; }
__device__ __forceinline__ float sigf(float v) { return 1.f / (1.f + __expf(-v)); }
__device__ __forceinline__ double leakyd(double v) { return v >= 0. ? v : 0.01 * v; }

// f32 -> bf16 (RNE)
__device__ __forceinline__ uint32_t bf16rne(float x) {
  uint32_t b = __float_as_uint(x);
  return (b + 0x7FFFu + ((b >> 16) & 1u)) >> 16;
}
__device__ __forceinline__ float bf2f(short s) {
  return __uint_as_float(((uint32_t)(uint16_t)s) << 16);
}
// pack f32 -> (hi bf16) | (lo bf16 << 16)
__device__ __forceinline__ uint32_t packHL(float x) {
  const uint32_t hb = bf16rne(x);
  const float hf = __uint_as_float(hb << 16);
  const uint32_t lb = bf16rne(x - hf);
  return hb | (lb << 16);
}
__device__ __forceinline__ void unpack8(const uint32_t u[8], s16x8& h, s16x8& l) {
  #pragma unroll
  for (int j = 0; j < 8; ++j) { h[j] = (short)(u[j] & 0xffffu); l[j] = (short)(u[j] >> 16); }
}

// JAX threefry2x32 (20 rounds), key = (0, 42)
__device__ __forceinline__ void threefry(uint32_t x0, uint32_t x1, uint32_t& o0, uint32_t& o1) {
  const uint32_t ks0 = 0u, ks1 = 42u;
  const uint32_t ks2 = ks0 ^ ks1 ^ 0x1BD11BDAu;
  uint32_t ks[3] = {ks0, ks1, ks2};
  const int R0[4] = {13, 15, 26, 6};
  const int R1[4] = {17, 29, 16, 24};
  x0 += ks[0]; x1 += ks[1];
  #pragma unroll
  for (int g = 0; g < 5; ++g) {
    const int* R = (g & 1) ? R1 : R0;
    #pragma unroll
    for (int i = 0; i < 4; ++i) {
      x0 += x1;
      x1 = (x1 << R[i]) | (x1 >> (32 - R[i]));
      x1 ^= x0;
    }
    x0 += ks[(g + 1) % 3];
    x1 += ks[(g + 2) % 3] + (uint32_t)(g + 1);
  }
  o0 = x0; o1 = x1;
}

// ---------------- fused MFMA GEMM: Fp[kz]=adj@X, Gp[iz]=adj^T@X ----------------
// bf16 hi/lo split (3 MFMA) ~ f32 accuracy. grid (64 iz, 32 kz), block 256 = 4 waves.
// Tile 128 i x 256 k (8 chunks of 32 k). adj read from global ONCE (staging only).
// waves 0,1: fwd — A-frags via strided b32 reads from aP (4-way fg-alias, cheap) + unpack.
// waves 2,3: tr  — A-frags via uint4 reads from aP + unpack. B operands from XkH/XkL / X2h/X2l.
template <int C, bool SUMS>
__global__ __launch_bounds__(256) void k_gemm(const float* __restrict__ adj,
                                              const float* __restrict__ X,
                                              float* __restrict__ Fp,
                                              float* __restrict__ Gp,
                                              float* __restrict__ rsP,
                                              float* __restrict__ csP) {
  constexpr int NT = C / 16;
  __shared__ alignas(16) uint32_t aP[32 * 132];  // adj chunk k-major, packed hi|lo<<16
  __shared__ alignas(16) short X2h[C * 136];     // X rows I0..I0+127 transposed, bf16 hi
  __shared__ alignas(16) short X2l[C * 136];
  __shared__ alignas(16) short XkH[C * 40];      // X chunk transposed [c][32 k], bf16 hi
  __shared__ alignas(16) short XkL[C * 40];
  const int t = threadIdx.x;
  const int iz = blockIdx.x;      // 0..63
  const int kz = blockIdx.y;      // 0..31
  const int I0 = iz * 128;
  const int K0 = kz * 256;
  const int lane = t & 63;
  const int wid = t >> 6;
  const int fm = lane & 15;
  const int fg = lane >> 4;

  // ---- stage X2 (rows I0..I0+127, transposed, bf16 hi/lo) ----
  if constexpr (C == 32) {
    #pragma unroll
    for (int r = 0; r < 4; ++r) {
      const int i = r * 32 + (t >> 3);
      const int c4 = 4 * (t & 7);
      const float4 v = *(const float4*)&X[(size_t)(I0 + i) * 32 + c4];
      const float vv[4] = {v.x, v.y, v.z, v.w};
      #pragma unroll
      for (int j = 0; j < 4; ++j) {
        const uint32_t p = packHL(vv[j]);
        X2h[(c4 + j) * 136 + i] = (short)(p & 0xffffu);
        X2l[(c4 + j) * 136 + i] = (short)(p >> 16);
      }
    }
  } else {
    if (t < 128) {
      #pragma unroll
      for (int r = 0; r < 4; ++r) {
        const int i = r * 32 + (t >> 2);
        const int c4 = 4 * (t & 3);
        const float4 v = *(const float4*)&X[(size_t)(I0 + i) * 16 + c4];
        const float vv[4] = {v.x, v.y, v.z, v.w};
        #pragma unroll
        for (int j = 0; j < 4; ++j) {
          const uint32_t p = packHL(vv[j]);
          X2h[(c4 + j) * 136 + i] = (short)(p & 0xffffu);
          X2l[(c4 + j) * 136 + i] = (short)(p >> 16);
        }
      }
    }
  }

  f32x4 accF[4][NT];
  #pragma unroll
  for (int mt = 0; mt < 4; ++mt)
    #pragma unroll
    for (int nt = 0; nt < NT; ++nt) accF[mt][nt] = (f32x4){0.f, 0.f, 0.f, 0.f};
  float rs[4] = {0.f, 0.f, 0.f, 0.f};

  const int rb = t >> 3;          // staging: i-lane 0..31
  const int k4 = 4 * (t & 7);     // staging: k-quad 0,4,..28

  for (int ch = 0; ch < 8; ++ch) {
    const int kb = K0 + ch * 32;
    __syncthreads();
    // ---- stage adj chunk -> aP (k-major packed u32) ----
    #pragma unroll
    for (int q = 0; q < 4; ++q) {
      const int i = q * 32 + rb;
      const float4 v = *(const float4*)&adj[(size_t)(I0 + i) * NROW + kb + k4];
      const float vv[4] = {v.x, v.y, v.z, v.w};
      #pragma unroll
      for (int j = 0; j < 4; ++j) aP[(k4 + j) * 132 + i] = packHL(vv[j]);
    }
    // ---- stage Xk ----
    if constexpr (C == 32) {
      const int k = t >> 3, c4 = 4 * (t & 7);
      const float4 v = *(const float4*)&X[(size_t)(kb + k) * 32 + c4];
      const float vv[4] = {v.x, v.y, v.z, v.w};
      #pragma unroll
      for (int j = 0; j < 4; ++j) {
        const uint32_t p = packHL(vv[j]);
        XkH[(c4 + j) * 40 + k] = (short)(p & 0xffffu);
        XkL[(c4 + j) * 40 + k] = (short)(p >> 16);
      }
    } else {
      if (t < 128) {
        const int k = t >> 2, c4 = 4 * (t & 3);
        const float4 v = *(const float4*)&X[(size_t)(kb + k) * 16 + c4];
        const float vv[4] = {v.x, v.y, v.z, v.w};
        #pragma unroll
        for (int j = 0; j < 4; ++j) {
          const uint32_t p = packHL(vv[j]);
          XkH[(c4 + j) * 40 + k] = (short)(p & 0xffffu);
          XkL[(c4 + j) * 40 + k] = (short)(p >> 16);
        }
      }
    }
    __syncthreads();
    if (wid < 2) {
      // ---- fwd: A-frags from aP via strided b32 reads (row fm, k = 8*fg+j). No global re-read. ----
      s16x8 bh[NT], bl[NT];
      #pragma unroll
      for (int nt = 0; nt < NT; ++nt) {
        bh[nt] = *(const s16x8*)&XkH[(nt * 16 + fm) * 40 + 8 * fg];
        bl[nt] = *(const s16x8*)&XkL[(nt * 16 + fm) * 40 + 8 * fg];
      }
      #pragma unroll
      for (int mt = 0; mt < 4; ++mt) {
        const int rowl = (wid * 4 + mt) * 16 + fm;   // local row 0..127
        uint32_t u[8];
        #pragma unroll
        for (int j = 0; j < 8; ++j) u[j] = aP[(8 * fg + j) * 132 + rowl];
        s16x8 ah, al;
        unpack8(u, ah, al);
        if (SUMS) {
          #pragma unroll
          for (int j = 0; j < 8; ++j) rs[mt] += fabsf(bf2f(ah[j]) + bf2f(al[j]));
        }
        #pragma unroll
        for (int nt = 0; nt < NT; ++nt) {
          accF[mt][nt] = __builtin_amdgcn_mfma_f32_16x16x32_bf16(ah, bh[nt], accF[mt][nt], 0, 0, 0);
          accF[mt][nt] = __builtin_amdgcn_mfma_f32_16x16x32_bf16(ah, bl[nt], accF[mt][nt], 0, 0, 0);
          accF[mt][nt] = __builtin_amdgcn_mfma_f32_16x16x32_bf16(al, bh[nt], accF[mt][nt], 0, 0, 0);
        }
      }
    } else {
      // ---- tr: A-frags from aP (uint4 b128 reads + unpack). ----
      const int kt = wid - 2;
      f32x4 accT[NT];
      #pragma unroll
      for (int ct = 0; ct < NT; ++ct) accT[ct] = (f32x4){0.f, 0.f, 0.f, 0.f};
      float cs = 0.f;
      #pragma unroll
      for (int iw = 0; iw < 4; ++iw) {
        const uint32_t* ap = &aP[(kt * 16 + fm) * 132 + iw * 32 + 8 * fg];
        const uint4 ua = *(const uint4*)ap;
        const uint4 ub = *(const uint4*)(ap + 4);
        const uint32_t u[8] = {ua.x, ua.y, ua.z, ua.w, ub.x, ub.y, ub.z, ub.w};
        s16x8 ah, al;
        unpack8(u, ah, al);
        if (SUMS) {
          #pragma unroll
          for (int j = 0; j < 8; ++j) cs += fabsf(bf2f(ah[j]) + bf2f(al[j]));
        }
        #pragma unroll
        for (int ct = 0; ct < NT; ++ct) {
          const s16x8 xh = *(const s16x8*)&X2h[(ct * 16 + fm) * 136 + iw * 32 + 8 * fg];
          const s16x8 xl = *(const s16x8*)&X2l[(ct * 16 + fm) * 136 + iw * 32 + 8 * fg];
          accT[ct] = __builtin_amdgcn_mfma_f32_16x16x32_bf16(ah, xh, accT[ct], 0, 0, 0);
          accT[ct] = __builtin_amdgcn_mfma_f32_16x16x32_bf16(ah, xl, accT[ct], 0, 0, 0);
          accT[ct] = __builtin_amdgcn_mfma_f32_16x16x32_bf16(al, xh, accT[ct], 0, 0, 0);
        }
      }
      #pragma unroll
      for (int ct = 0; ct < NT; ++ct)
        #pragma unroll
        for (int r = 0; r < 4; ++r)
          Gp[((size_t)iz * NROW + kb + kt * 16 + 4 * fg + r) * 32 + ct * 16 + fm] = accT[ct][r];
      if (SUMS) {
        cs += __shfl_xor(cs, 16, 64);
        cs += __shfl_xor(cs, 32, 64);
        if (lane < 16) csP[(size_t)iz * NROW + kb + kt * 16 + lane] = cs;
      }
    }
  }
  // ---- fwd epilogue: write Fp (+rsP) ----
  if (wid < 2) {
    #pragma unroll
    for (int mt = 0; mt < 4; ++mt) {
      const int rowb = I0 + (wid * 4 + mt) * 16;
      #pragma unroll
      for (int nt = 0; nt < NT; ++nt)
        #pragma unroll
        for (int r = 0; r < 4; ++r)
          Fp[((size_t)kz * NROW + rowb + 4 * fg + r) * 32 + nt * 16 + fm] = accF[mt][nt][r];
      if (SUMS) {
        float v = rs[mt];
        v += __shfl_xor(v, 16, 64);
        v += __shfl_xor(v, 32, 64);
        if (lane < 16) rsP[(size_t)kz * NROW + rowb + lane] = v;
      }
    }
  }
}

// ---------------- S1: fold pass1 (f64), build l1, v1, mean-l1 partials ----------------
// grid 256 (32 rows/block), block 256
__global__ __launch_bounds__(256) void k_s1(const float* __restrict__ Fp, const float* __restrict__ rsP,
                                            const float* __restrict__ Gp, const float* __restrict__ csP,
                                            const float* __restrict__ x,  const float* __restrict__ W1,
                                            const float* __restrict__ b1,
                                            float* __restrict__ rowsum, float* __restrict__ colsum,
                                            float* __restrict__ v1, float* __restrict__ mlp) {
  __shared__ float l1L[32 * 100];
  __shared__ float rsL[32], csL[32];
  const int t = threadIdx.x;
  const int n0 = blockIdx.x * 32;
  if (t < 32) {
    double s = 0.;
    for (int p = 0; p < 32; ++p) s += (double)rsP[(size_t)p * NROW + n0 + t];
    s = fmax(s, 1e-12);
    rowsum[n0 + t] = (float)s; rsL[t] = (float)s;
  } else if (t < 64) {
    const int r = t - 32;
    double s = 0.;
    for (int p = 0; p < 64; ++p) s += (double)csP[(size_t)p * NROW + n0 + r];
    s = fmax(s, 1e-12);
    colsum[n0 + r] = (float)s; csL[r] = (float)s;
  }
  __syncthreads();
  {
    const int r = t >> 3, c = (t & 7) * 4;
    const int n = n0 + r;
    double s[4] = {0., 0., 0., 0.};
    for (int p = 0; p < 32; ++p) {
      const float4 v = *(const float4*)&Fp[((size_t)p * NROW + n) * 32 + c];
      s[0] += v.x; s[1] += v.y; s[2] += v.z; s[3] += v.w;
    }
    const double rsv = (double)rsL[r];
    #pragma unroll
    for (int q = 0; q < 4; ++q) l1L[r * 100 + c + q] = (float)(s[q] / rsv);
    double sg[4] = {0., 0., 0., 0.};
    for (int p = 0; p < 64; ++p) {
      const float4 v = *(const float4*)&Gp[((size_t)p * NROW + n) * 32 + c];
      sg[0] += v.x; sg[1] += v.y; sg[2] += v.z; sg[3] += v.w;
    }
    const double csv = (double)csL[r];
    #pragma unroll
    for (int q = 0; q < 4; ++q) l1L[r * 100 + 32 + c + q] = (float)(sg[q] / csv);
    *(float4*)&l1L[r * 100 + 64 + c] = *(const float4*)&x[(size_t)n * 32 + c];
  }
  __syncthreads();
  if (t < 96) {
    double s = 0.;
    for (int r = 0; r < 32; ++r) s += (double)l1L[r * 100 + t];
    mlp[(size_t)blockIdx.x * 96 + t] = (float)s;
  }
  {
    const int r = t & 31, jg = t >> 5;
    const int n = n0 + r;
    float accv[4];
    #pragma unroll
    for (int jj = 0; jj < 4; ++jj) accv[jj] = b1[4 * jg + jj];
    for (int k = 0; k < 96; k += 4) {
      const float4 lv = *(const float4*)&l1L[r * 100 + k];
      #pragma unroll
      for (int jj = 0; jj < 4; ++jj) {
        const float4 wv = *(const float4*)&W1[(size_t)(4 * jg + jj) * 96 + k];
        accv[jj] += lv.x * wv.x + lv.y * wv.y + lv.z * wv.z + lv.w * wv.w;
      }
    }
    #pragma unroll
    for (int jj = 0; jj < 4; ++jj) v1[(size_t)n * 32 + 4 * jg + jj] = leaky(accv[jj]);
  }
}

// ---------------- S2: u1 (f64 folds) ----------------
__global__ void k_s2(const float* __restrict__ mlp, const float* __restrict__ uW1,
                     const float* __restrict__ ub1, float* __restrict__ u1) {
  __shared__ float ml[96];
  const int t = threadIdx.x;  // block 128
  if (t < 96) {
    double s = 0.;
    for (int b = 0; b < 256; ++b) s += (double)mlp[(size_t)b * 96 + t];
    ml[t] = (float)(s * (1.0 / 8192.0));
  }
  __syncthreads();
  if (t < 16) {
    double a = (double)ub1[t];
    for (int k = 0; k < 96; ++k) a += (double)ml[k] * (double)uW1[(size_t)t * 96 + k];
    u1[t] = (float)leakyd(a);
  }
}

// ---------------- S4: fold pass2 -> vec LDS; per-thread one gate row; LSTM combine ----------------
// grid 512 (16 rows/block), block 256
__global__ __launch_bounds__(256) void k_s4(const float* __restrict__ Fp, const float* __restrict__ Gp,
                                            const float* __restrict__ v1, const float* __restrict__ u1,
                                            const float* __restrict__ rowsum, const float* __restrict__ colsum,
                                            const float* __restrict__ Wih, const float* __restrict__ Whh,
                                            const float* __restrict__ bih, const float* __restrict__ bhh,
                                            const float* __restrict__ h_in, const float* __restrict__ c_in,
                                            float* __restrict__ out, float* __restrict__ v2,
                                            float* __restrict__ u2p) {
  __shared__ float vecL[16 * 148];    // [u1(16) | Av1(32) | ATv1(32) | v1(32) | h(32)] per row
  __shared__ float gL[16 * 132];      // gates [row][128] (+4 pad)
  __shared__ float rsL[16], csL[16];
  __shared__ float hoL[16 * 17];      // h_out cols 16..31
  const int t = threadIdx.x;
  const int n0 = blockIdx.x * 16;
  if (t < 16) rsL[t] = rowsum[n0 + t];
  else if (t < 32) csL[t - 16] = colsum[n0 + t - 16];
  { const int r = t >> 4, k = t & 15; vecL[r * 148 + k] = u1[k]; }
  __syncthreads();
  // ---- Phase A: fold split-K partials into vec ----
  {
    const int r = t >> 4, q = t & 15;
    const int n = n0 + r;
    if (q < 8) {
      const int c = q * 4;
      float4 s = {0.f, 0.f, 0.f, 0.f};
      for (int p = 0; p < 32; ++p) {
        const float4 v = *(const float4*)&Fp[((size_t)p * NROW + n) * 32 + c];
        s.x += v.x; s.y += v.y; s.z += v.z; s.w += v.w;
      }
      const float rsv = rsL[r];
      float4 o = {s.x / rsv, s.y / rsv, s.z / rsv, s.w / rsv};
      *(float4*)&vecL[r * 148 + 16 + c] = o;
      *(float4*)&vecL[r * 148 + 80 + c] = *(const float4*)&v1[(size_t)n * 32 + c];
    } else {
      const int c = (q - 8) * 4;
      float4 s = {0.f, 0.f, 0.f, 0.f};
      for (int p = 0; p < 64; ++p) {
        const float4 v = *(const float4*)&Gp[((size_t)p * NROW + n) * 32 + c];
        s.x += v.x; s.y += v.y; s.z += v.z; s.w += v.w;
      }
      const float csv = csL[r];
      float4 o = {s.x / csv, s.y / csv, s.z / csv, s.w / csv};
      *(float4*)&vecL[r * 148 + 48 + c] = o;
      *(float4*)&vecL[r * 148 + 112 + c] = *(const float4*)&h_in[(size_t)n * 32 + c];
    }
  }
  __syncthreads();
  // ---- Phase B: gates. gate = t&127, 8 rows each ----
  {
    const int gate = t & 127;
    const int half = t >> 7;
    const float bias = bih[gate] + bhh[gate];
    float acc[8];
    #pragma unroll
    for (int rr = 0; rr < 8; ++rr) acc[rr] = bias;
    const float* __restrict__ Wrow = Wih + (size_t)gate * 112;
    const float* __restrict__ vbase = vecL + (half * 8) * 148;
    #pragma unroll 4
    for (int kq = 0; kq < 28; ++kq) {
      const float4 w = *(const float4*)&Wrow[kq * 4];
      #pragma unroll
      for (int rr = 0; rr < 8; ++rr) {
        const float4 v = *(const float4*)&vbase[rr * 148 + kq * 4];
        acc[rr] += w.x * v.x + w.y * v.y + w.z * v.z + w.w * v.w;
      }
    }
    const float* __restrict__ Hrow = Whh + (size_t)gate * 32;
    #pragma unroll 4
    for (int kq = 0; kq < 8; ++kq) {
      const float4 w = *(const float4*)&Hrow[kq * 4];
      #pragma unroll
      for (int rr = 0; rr < 8; ++rr) {
        const float4 v = *(const float4*)&vbase[rr * 148 + 112 + kq * 4];
        acc[rr] += w.x * v.x + w.y * v.y + w.z * v.z + w.w * v.w;
      }
    }
    #pragma unroll
    for (int rr = 0; rr < 8; ++rr) gL[(half * 8 + rr) * 132 + gate] = acc[rr];
  }
  __syncthreads();
  // ---- Phase C: LSTM combine, outputs ----
  #pragma unroll
  for (int it = 0; it < 2; ++it) {
    const int w = it * 256 + t;
    const int r = w >> 5, j = w & 31;
    const int n = n0 + r;
    const float iv = gL[r * 132 + j];
    const float fv = gL[r * 132 + 32 + j];
    const float gv = gL[r * 132 + 64 + j];
    const float ov = gL[r * 132 + 96 + j];
    const float cv = c_in[(size_t)n * 32 + j];
    const float cn = sigf(fv) * cv + sigf(iv) * tanhf(gv);
    const float hn = sigf(ov) * tanhf(cn);
    out[8192 + (size_t)n * 32 + j] = hn;
    out[8192 + 262144 + (size_t)n * 32 + j] = cn;
    if (j < 16) v2[(size_t)n * 16 + j] = leaky(hn);
    else hoL[r * 17 + (j - 16)] = hn;
  }
  __syncthreads();
  if (t < 16) {
    float s = 0.f;
    for (int r2 = 0; r2 < 16; ++r2) s += hoL[r2 * 17 + t];
    u2p[(size_t)blockIdx.x * 16 + t] = s;
  }
}

// ---------------- S5: u2 (f64 fold) ----------------
__global__ void k_s5(const float* __restrict__ u2p, float* __restrict__ u2) {
  const int t = threadIdx.x;  // block 64
  if (t < 16) {
    double s = 0.;
    for (int b = 0; b < 512; ++b) s += (double)u2p[(size_t)b * 16 + t];
    u2[t] = (float)leakyd(s * (1.0 / 8192.0));
  }
}

// ---------------- S6: fold pass3 (f64), layer3 (f64), logits, gumbel-argmax ----------------
// grid 128 (64 rows/block), block 256
// RNG: JAX partitionable threefry: (o0,o1)=threefry2x32(key,(0,m)); bits = o0^o1. VERIFIED r4.
__global__ __launch_bounds__(256) void k_s6(const float* __restrict__ Fp, const float* __restrict__ Gp,
                                            const float* __restrict__ v2, const float* __restrict__ u2,
                                            const float* __restrict__ rowsum, const float* __restrict__ colsum,
                                            const float* __restrict__ W3, const float* __restrict__ b3,
                                            float* __restrict__ out) {
  __shared__ float l3L[64 * 68];
  __shared__ float w3L[192];
  __shared__ float b3L[3];
  __shared__ double lgL[64 * 4];
  __shared__ float rsL[64], csL[64];
  const int t = threadIdx.x;
  const int n0 = blockIdx.x * 64;
  if (t < 192) w3L[t] = W3[t];
  if (t < 3) b3L[t] = b3[t];
  if (t < 64) rsL[t] = rowsum[n0 + t];
  else if (t < 128) csL[t - 64] = colsum[n0 + t - 64];
  __syncthreads();
  {
    const int r = t >> 2, q = t & 3;
    const int n = n0 + r;
    if (q == 0) {
      #pragma unroll
      for (int cc = 0; cc < 4; ++cc) *(float4*)&l3L[r * 68 + cc * 4] = *(const float4*)&u2[cc * 4];
    } else if (q == 1) {
      const double rsv = (double)rsL[r];
      #pragma unroll
      for (int cc = 0; cc < 4; ++cc) {
        const int c = cc * 4;
        double s[4] = {0., 0., 0., 0.};
        for (int p = 0; p < 32; ++p) {
          const float4 v = *(const float4*)&Fp[((size_t)p * NROW + n) * 32 + c];
          s[0] += v.x; s[1] += v.y; s[2] += v.z; s[3] += v.w;
        }
        #pragma unroll
        for (int q2 = 0; q2 < 4; ++q2) l3L[r * 68 + 16 + c + q2] = (float)(s[q2] / rsv);
      }
    } else if (q == 2) {
      const double csv = (double)csL[r];
      #pragma unroll
      for (int cc = 0; cc < 4; ++cc) {
        const int c = cc * 4;
        double s[4] = {0., 0., 0., 0.};
        for (int p = 0; p < 64; ++p) {
          const float4 v = *(const float4*)&Gp[((size_t)p * NROW + n) * 32 + c];
          s[0] += v.x; s[1] += v.y; s[2] += v.z; s[3] += v.w;
        }
        #pragma unroll
        for (int q2 = 0; q2 < 4; ++q2) l3L[r * 68 + 32 + c + q2] = (float)(s[q2] / csv);
      }
    } else {
      #pragma unroll
      for (int cc = 0; cc < 4; ++cc)
        *(float4*)&l3L[r * 68 + 48 + cc * 4] = *(const float4*)&v2[(size_t)n * 16 + cc * 4];
    }
  }
  __syncthreads();
  {
    const int r = t >> 2, q = t & 3;
    if (q < 3) {
      double a = (double)b3L[q];
      for (int k = 0; k < 64; ++k) a += (double)l3L[r * 68 + k] * (double)w3L[q * 64 + k];
      lgL[r * 4 + q] = 2.0 * tanh(a);
    }
  }
  __syncthreads();
  if ((t & 3) == 0) {
    const int r = t >> 2;
    const int n = n0 + r;
    int best = 0;
    double bv = -1.0e300;
    #pragma unroll
    for (int j = 0; j < 3; ++j) {
      const uint32_t m = (uint32_t)(n * 3 + j);
      uint32_t o0, o1;
      threefry(0u, m, o0, o1);           // partitionable: counter64 = m -> (hi=0, lo=m)
      const uint32_t bits = o0 ^ o1;     // 32-bit output word
      const float f = __uint_as_float((bits >> 9) | 0x3f800000u) - 1.0f;
      const double u = fmax((double)f, 1.17549435e-38);
      const double g = -log(-log(u));
      const double val = g + lgL[r * 4 + j];
      if (val > bv) { bv = val; best = j; }
    }
    out[n] = (float)best - 1.0f;
  }
}

// ---------------- launch ----------------
extern "C" void kernel_launch(void* const* d_in, const int* in_sizes, int n_in,
                              void* d_out, int out_size, void* d_ws, size_t ws_size,
                              hipStream_t stream) {
  const float* adj = (const float*)d_in[0];
  const float* x   = (const float*)d_in[1];
  const float* h   = (const float*)d_in[2];
  const float* c   = (const float*)d_in[3];
  const float* W1  = (const float*)d_in[4];
  const float* b1  = (const float*)d_in[5];
  const float* uW1 = (const float*)d_in[6];
  const float* ub1 = (const float*)d_in[7];
  const float* Wih = (const float*)d_in[8];
  const float* Whh = (const float*)d_in[9];
  const float* bih = (const float*)d_in[10];
  const float* bhh = (const float*)d_in[11];
  const float* W3  = (const float*)d_in[12];
  const float* b3  = (const float*)d_in[13];
  float* out = (float*)d_out;
  float* ws  = (float*)d_ws;

  float* Fp  = ws + W_FP;
  float* Gp  = ws + W_GP;
  float* rsP = ws + W_RSP;
  float* csP = ws + W_CSP;
  float* rs  = ws + W_RS;
  float* cs  = ws + W_CS;
  float* v1  = ws + W_V1;
  float* v2  = ws + W_V2;
  float* u1  = ws + W_U1;
  float* u2  = ws + W_U2;
  float* mlp = ws + W_MLP;
  float* u2p = ws + W_U2P;

  // ---- pass 1: adj @ x AND adj.T @ x (+ row/col sums) ----
  k_gemm<32, true><<<dim3(64, 32), 256, 0, stream>>>(adj, x, Fp, Gp, rsP, csP);
  k_s1<<<256, 256, 0, stream>>>(Fp, rsP, Gp, csP, x, W1, b1, rs, cs, v1, mlp);
  k_s2<<<1, 128, 0, stream>>>(mlp, uW1, ub1, u1);

  // ---- pass 2: adj @ v1 AND adj.T @ v1 ; LSTM ----
  k_gemm<32, false><<<dim3(64, 32), 256, 0, stream>>>(adj, v1, Fp, Gp, nullptr, nullptr);
  k_s4<<<512, 256, 0, stream>>>(Fp, Gp, v1, u1, rs, cs, Wih, Whh, bih, bhh, h, c, out, v2, u2p);
  k_s5<<<1, 64, 0, stream>>>(u2p, u2);

  // ---- pass 3: adj @ v2 AND adj.T @ v2 ; layer3 + sampling ----
  k_gemm<16, false><<<dim3(64, 32), 256, 0, stream>>>(adj, v2, Fp, Gp, nullptr, nullptr);
  k_s6<<<128, 256, 0, stream>>>(Fp, Gp, v2, u2, rs, cs, W3, b3, out);
}

// Round 17
// 343.224 us; speedup vs baseline: 1.7537x; 1.0834x over previous
//
#include <hip/hip_runtime.h>
#include <stdint.h>
#include <math.h>

#define NROW 8192
// dims: IN=32, G=16, H1=32, H2=16, LSTM_HID = 32
// out: actions[8192], h_out @ 8192, c_out @ 270336

// ---------------- workspace layout (floats, in d_ws; ws_size = 1 GiB) ----------------
constexpr size_t W_FP  = 0;                              // fwd partials [32][8192][32] (C=16 pass packs stride 16)
constexpr size_t W_GP  = W_FP  + (size_t)32*NROW*32;     // tr  partials [64][8192][32] (C=16 pass packs stride 16)
constexpr size_t W_RSP = W_GP  + (size_t)64*NROW*32;     // rowsum partials [32][8192]
constexpr size_t W_CSP = W_RSP + (size_t)32*NROW;        // colsum partials [64][8192]
constexpr size_t W_RS  = W_CSP + (size_t)64*NROW;        // rowsum [8192]
constexpr size_t W_CS  = W_RS  + NROW;                   // colsum [8192]
constexpr size_t W_V1  = W_CS  + NROW;                   // v1 [8192][32]
constexpr size_t W_V2  = W_V1  + (size_t)NROW*32;        // v2 [8192][16]
constexpr size_t W_U1  = W_V2  + (size_t)NROW*16;        // u1 [16]
constexpr size_t W_MLP = W_U1  + 16;                     // l1-mean partials [256][96]
constexpr size_t W_U2P = W_MLP + (size_t)256*96;         // u2 partials [512][16]

typedef float f32x4 __attribute__((ext_vector_type(4)));
typedef short s16x8 __attribute__((ext_vector_type(8)));

__device__ __forceinline__ float leaky(float v) { return v >= 0.f ? v : 0.01f * v; }
__device__ __forceinline__ float sigf(float v) { return 1.f / (1.f + __expf(-v)); }
__device__ __forceinline__ double leakyd(double v) { return v >= 0. ? v : 0.01 * v; }

// f32 -> bf16 (RNE)
__device__ __forceinline__ uint32_t bf16rne(float x) {
  uint32_t b = __float_as_uint(x);
  return (b + 0x7FFFu + ((b >> 16) & 1u)) >> 16;
}
__device__ __forceinline__ float bf2f(short s) {
  return __uint_as_float(((uint32_t)(uint16_t)s) << 16);
}
// pack f32 -> (hi bf16) | (lo bf16 << 16)
__device__ __forceinline__ uint32_t packHL(float x) {
  const uint32_t hb = bf16rne(x);
  const float hf = __uint_as_float(hb << 16);
  const uint32_t lb = bf16rne(x - hf);
  return hb | (lb << 16);
}
__device__ __forceinline__ void unpack8(const uint32_t u[8], s16x8& h, s16x8& l) {
  #pragma unroll
  for (int j = 0; j < 8; ++j) { h[j] = (short)(u[j] & 0xffffu); l[j] = (short)(u[j] >> 16); }
}

// JAX threefry2x32 (20 rounds), key = (0, 42)
__device__ __forceinline__ void threefry(uint32_t x0, uint32_t x1, uint32_t& o0, uint32_t& o1) {
  const uint32_t ks0 = 0u, ks1 = 42u;
  const uint32_t ks2 = ks0 ^ ks1 ^ 0x1BD11BDAu;
  uint32_t ks[3] = {ks0, ks1, ks2};
  const int R0[4] = {13, 15, 26, 6};
  const int R1[4] = {17, 29, 16, 24};
  x0 += ks[0]; x1 += ks[1];
  #pragma unroll
  for (int g = 0; g < 5; ++g) {
    const int* R = (g & 1) ? R1 : R0;
    #pragma unroll
    for (int i = 0; i < 4; ++i) {
      x0 += x1;
      x1 = (x1 << R[i]) | (x1 >> (32 - R[i]));
      x1 ^= x0;
    }
    x0 += ks[(g + 1) % 3];
    x1 += ks[(g + 2) % 3] + (uint32_t)(g + 1);
  }
  o0 = x0; o1 = x1;
}

// ---------------- fused MFMA GEMM: Fp[kz]=adj@X, Gp[iz]=adj^T@X (stride C) ----------------
// bf16 hi/lo split (3 MFMA) ~ f32 accuracy. grid (64 iz, 32 kz), block 256 = 4 waves.
// Tile 128 i x 256 k (8 chunks of 32 k). adj read from global ONCE (staging only).
// waves 0,1: fwd — A-frags via strided b32 reads from aP + unpack.
// waves 2,3: tr  — A-frags via uint4 reads from aP + unpack. B operands from XkH/XkL / X2h/X2l.
template <int C, bool SUMS>
__global__ __launch_bounds__(256) void k_gemm(const float* __restrict__ adj,
                                              const float* __restrict__ X,
                                              float* __restrict__ Fp,
                                              float* __restrict__ Gp,
                                              float* __restrict__ rsP,
                                              float* __restrict__ csP) {
  constexpr int NT = C / 16;
  __shared__ alignas(16) uint32_t aP[32 * 132];  // adj chunk k-major, packed hi|lo<<16
  __shared__ alignas(16) short X2h[C * 136];     // X rows I0..I0+127 transposed, bf16 hi
  __shared__ alignas(16) short X2l[C * 136];
  __shared__ alignas(16) short XkH[C * 40];      // X chunk transposed [c][32 k], bf16 hi
  __shared__ alignas(16) short XkL[C * 40];
  const int t = threadIdx.x;
  const int iz = blockIdx.x;      // 0..63
  const int kz = blockIdx.y;      // 0..31
  const int I0 = iz * 128;
  const int K0 = kz * 256;
  const int lane = t & 63;
  const int wid = t >> 6;
  const int fm = lane & 15;
  const int fg = lane >> 4;

  // ---- stage X2 (rows I0..I0+127, transposed, bf16 hi/lo) ----
  if constexpr (C == 32) {
    #pragma unroll
    for (int r = 0; r < 4; ++r) {
      const int i = r * 32 + (t >> 3);
      const int c4 = 4 * (t & 7);
      const float4 v = *(const float4*)&X[(size_t)(I0 + i) * 32 + c4];
      const float vv[4] = {v.x, v.y, v.z, v.w};
      #pragma unroll
      for (int j = 0; j < 4; ++j) {
        const uint32_t p = packHL(vv[j]);
        X2h[(c4 + j) * 136 + i] = (short)(p & 0xffffu);
        X2l[(c4 + j) * 136 + i] = (short)(p >> 16);
      }
    }
  } else {
    if (t < 128) {
      #pragma unroll
      for (int r = 0; r < 4; ++r) {
        const int i = r * 32 + (t >> 2);
        const int c4 = 4 * (t & 3);
        const float4 v = *(const float4*)&X[(size_t)(I0 + i) * 16 + c4];
        const float vv[4] = {v.x, v.y, v.z, v.w};
        #pragma unroll
        for (int j = 0; j < 4; ++j) {
          const uint32_t p = packHL(vv[j]);
          X2h[(c4 + j) * 136 + i] = (short)(p & 0xffffu);
          X2l[(c4 + j) * 136 + i] = (short)(p >> 16);
        }
      }
    }
  }

  f32x4 accF[4][NT];
  #pragma unroll
  for (int mt = 0; mt < 4; ++mt)
    #pragma unroll
    for (int nt = 0; nt < NT; ++nt) accF[mt][nt] = (f32x4){0.f, 0.f, 0.f, 0.f};
  float rs[4] = {0.f, 0.f, 0.f, 0.f};

  const int rb = t >> 3;          // staging: i-lane 0..31
  const int k4 = 4 * (t & 7);     // staging: k-quad 0,4,..28

  for (int ch = 0; ch < 8; ++ch) {
    const int kb = K0 + ch * 32;
    __syncthreads();
    // ---- stage adj chunk -> aP (k-major packed u32) ----
    #pragma unroll
    for (int q = 0; q < 4; ++q) {
      const int i = q * 32 + rb;
      const float4 v = *(const float4*)&adj[(size_t)(I0 + i) * NROW + kb + k4];
      const float vv[4] = {v.x, v.y, v.z, v.w};
      #pragma unroll
      for (int j = 0; j < 4; ++j) aP[(k4 + j) * 132 + i] = packHL(vv[j]);
    }
    // ---- stage Xk ----
    if constexpr (C == 32) {
      const int k = t >> 3, c4 = 4 * (t & 7);
      const float4 v = *(const float4*)&X[(size_t)(kb + k) * 32 + c4];
      const float vv[4] = {v.x, v.y, v.z, v.w};
      #pragma unroll
      for (int j = 0; j < 4; ++j) {
        const uint32_t p = packHL(vv[j]);
        XkH[(c4 + j) * 40 + k] = (short)(p & 0xffffu);
        XkL[(c4 + j) * 40 + k] = (short)(p >> 16);
      }
    } else {
      if (t < 128) {
        const int k = t >> 2, c4 = 4 * (t & 3);
        const float4 v = *(const float4*)&X[(size_t)(kb + k) * 16 + c4];
        const float vv[4] = {v.x, v.y, v.z, v.w};
        #pragma unroll
        for (int j = 0; j < 4; ++j) {
          const uint32_t p = packHL(vv[j]);
          XkH[(c4 + j) * 40 + k] = (short)(p & 0xffffu);
          XkL[(c4 + j) * 40 + k] = (short)(p >> 16);
        }
      }
    }
    __syncthreads();
    if (wid < 2) {
      // ---- fwd: A-frags from aP via strided b32 reads (row fm, k = 8*fg+j). ----
      s16x8 bh[NT], bl[NT];
      #pragma unroll
      for (int nt = 0; nt < NT; ++nt) {
        bh[nt] = *(const s16x8*)&XkH[(nt * 16 + fm) * 40 + 8 * fg];
        bl[nt] = *(const s16x8*)&XkL[(nt * 16 + fm) * 40 + 8 * fg];
      }
      #pragma unroll
      for (int mt = 0; mt < 4; ++mt) {
        const int rowl = (wid * 4 + mt) * 16 + fm;   // local row 0..127
        uint32_t u[8];
        #pragma unroll
        for (int j = 0; j < 8; ++j) u[j] = aP[(8 * fg + j) * 132 + rowl];
        s16x8 ah, al;
        unpack8(u, ah, al);
        if (SUMS) {
          #pragma unroll
          for (int j = 0; j < 8; ++j) rs[mt] += fabsf(bf2f(ah[j]) + bf2f(al[j]));
        }
        #pragma unroll
        for (int nt = 0; nt < NT; ++nt) {
          accF[mt][nt] = __builtin_amdgcn_mfma_f32_16x16x32_bf16(ah, bh[nt], accF[mt][nt], 0, 0, 0);
          accF[mt][nt] = __builtin_amdgcn_mfma_f32_16x16x32_bf16(ah, bl[nt], accF[mt][nt], 0, 0, 0);
          accF[mt][nt] = __builtin_amdgcn_mfma_f32_16x16x32_bf16(al, bh[nt], accF[mt][nt], 0, 0, 0);
        }
      }
    } else {
      // ---- tr: A-frags from aP (uint4 b128 reads + unpack). ----
      const int kt = wid - 2;
      f32x4 accT[NT];
      #pragma unroll
      for (int ct = 0; ct < NT; ++ct) accT[ct] = (f32x4){0.f, 0.f, 0.f, 0.f};
      float cs = 0.f;
      #pragma unroll
      for (int iw = 0; iw < 4; ++iw) {
        const uint32_t* ap = &aP[(kt * 16 + fm) * 132 + iw * 32 + 8 * fg];
        const uint4 ua = *(const uint4*)ap;
        const uint4 ub = *(const uint4*)(ap + 4);
        const uint32_t u[8] = {ua.x, ua.y, ua.z, ua.w, ub.x, ub.y, ub.z, ub.w};
        s16x8 ah, al;
        unpack8(u, ah, al);
        if (SUMS) {
          #pragma unroll
          for (int j = 0; j < 8; ++j) cs += fabsf(bf2f(ah[j]) + bf2f(al[j]));
        }
        #pragma unroll
        for (int ct = 0; ct < NT; ++ct) {
          const s16x8 xh = *(const s16x8*)&X2h[(ct * 16 + fm) * 136 + iw * 32 + 8 * fg];
          const s16x8 xl = *(const s16x8*)&X2l[(ct * 16 + fm) * 136 + iw * 32 + 8 * fg];
          accT[ct] = __builtin_amdgcn_mfma_f32_16x16x32_bf16(ah, xh, accT[ct], 0, 0, 0);
          accT[ct] = __builtin_amdgcn_mfma_f32_16x16x32_bf16(ah, xl, accT[ct], 0, 0, 0);
          accT[ct] = __builtin_amdgcn_mfma_f32_16x16x32_bf16(al, xh, accT[ct], 0, 0, 0);
        }
      }
      #pragma unroll
      for (int ct = 0; ct < NT; ++ct)
        #pragma unroll
        for (int r = 0; r < 4; ++r)
          Gp[((size_t)iz * NROW + kb + kt * 16 + 4 * fg + r) * C + ct * 16 + fm] = accT[ct][r];
      if (SUMS) {
        cs += __shfl_xor(cs, 16, 64);
        cs += __shfl_xor(cs, 32, 64);
        if (lane < 16) csP[(size_t)iz * NROW + kb + kt * 16 + lane] = cs;
      }
    }
  }
  // ---- fwd epilogue: write Fp (+rsP) ----
  if (wid < 2) {
    #pragma unroll
    for (int mt = 0; mt < 4; ++mt) {
      const int rowb = I0 + (wid * 4 + mt) * 16;
      #pragma unroll
      for (int nt = 0; nt < NT; ++nt)
        #pragma unroll
        for (int r = 0; r < 4; ++r)
          Fp[((size_t)kz * NROW + rowb + 4 * fg + r) * C + nt * 16 + fm] = accF[mt][nt][r];
      if (SUMS) {
        float v = rs[mt];
        v += __shfl_xor(v, 16, 64);
        v += __shfl_xor(v, 32, 64);
        if (lane < 16) rsP[(size_t)kz * NROW + rowb + lane] = v;
      }
    }
  }
}

// ---------------- S1: fold pass1 (f64), build l1, v1, mean-l1 partials ----------------
// grid 256 (32 rows/block), block 256
__global__ __launch_bounds__(256) void k_s1(const float* __restrict__ Fp, const float* __restrict__ rsP,
                                            const float* __restrict__ Gp, const float* __restrict__ csP,
                                            const float* __restrict__ x,  const float* __restrict__ W1,
                                            const float* __restrict__ b1,
                                            float* __restrict__ rowsum, float* __restrict__ colsum,
                                            float* __restrict__ v1, float* __restrict__ mlp) {
  __shared__ float l1L[32 * 100];
  __shared__ float rsL[32], csL[32];
  const int t = threadIdx.x;
  const int n0 = blockIdx.x * 32;
  if (t < 32) {
    double s = 0.;
    for (int p = 0; p < 32; ++p) s += (double)rsP[(size_t)p * NROW + n0 + t];
    s = fmax(s, 1e-12);
    rowsum[n0 + t] = (float)s; rsL[t] = (float)s;
  } else if (t < 64) {
    const int r = t - 32;
    double s = 0.;
    for (int p = 0; p < 64; ++p) s += (double)csP[(size_t)p * NROW + n0 + r];
    s = fmax(s, 1e-12);
    colsum[n0 + r] = (float)s; csL[r] = (float)s;
  }
  __syncthreads();
  {
    const int r = t >> 3, c = (t & 7) * 4;
    const int n = n0 + r;
    double s[4] = {0., 0., 0., 0.};
    for (int p = 0; p < 32; ++p) {
      const float4 v = *(const float4*)&Fp[((size_t)p * NROW + n) * 32 + c];
      s[0] += v.x; s[1] += v.y; s[2] += v.z; s[3] += v.w;
    }
    const double rsv = (double)rsL[r];
    #pragma unroll
    for (int q = 0; q < 4; ++q) l1L[r * 100 + c + q] = (float)(s[q] / rsv);
    double sg[4] = {0., 0., 0., 0.};
    for (int p = 0; p < 64; ++p) {
      const float4 v = *(const float4*)&Gp[((size_t)p * NROW + n) * 32 + c];
      sg[0] += v.x; sg[1] += v.y; sg[2] += v.z; sg[3] += v.w;
    }
    const double csv = (double)csL[r];
    #pragma unroll
    for (int q = 0; q < 4; ++q) l1L[r * 100 + 32 + c + q] = (float)(sg[q] / csv);
    *(float4*)&l1L[r * 100 + 64 + c] = *(const float4*)&x[(size_t)n * 32 + c];
  }
  __syncthreads();
  if (t < 96) {
    double s = 0.;
    for (int r = 0; r < 32; ++r) s += (double)l1L[r * 100 + t];
    mlp[(size_t)blockIdx.x * 96 + t] = (float)s;
  }
  {
    const int r = t & 31, jg = t >> 5;
    const int n = n0 + r;
    float accv[4];
    #pragma unroll
    for (int jj = 0; jj < 4; ++jj) accv[jj] = b1[4 * jg + jj];
    for (int k = 0; k < 96; k += 4) {
      const float4 lv = *(const float4*)&l1L[r * 100 + k];
      #pragma unroll
      for (int jj = 0; jj < 4; ++jj) {
        const float4 wv = *(const float4*)&W1[(size_t)(4 * jg + jj) * 96 + k];
        accv[jj] += lv.x * wv.x + lv.y * wv.y + lv.z * wv.z + lv.w * wv.w;
      }
    }
    #pragma unroll
    for (int jj = 0; jj < 4; ++jj) v1[(size_t)n * 32 + 4 * jg + jj] = leaky(accv[jj]);
  }
}

// ---------------- S2: u1 (f64 folds) ----------------
__global__ void k_s2(const float* __restrict__ mlp, const float* __restrict__ uW1,
                     const float* __restrict__ ub1, float* __restrict__ u1) {
  __shared__ float ml[96];
  const int t = threadIdx.x;  // block 128
  if (t < 96) {
    double s = 0.;
    for (int b = 0; b < 256; ++b) s += (double)mlp[(size_t)b * 96 + t];
    ml[t] = (float)(s * (1.0 / 8192.0));
  }
  __syncthreads();
  if (t < 16) {
    double a = (double)ub1[t];
    for (int k = 0; k < 96; ++k) a += (double)ml[k] * (double)uW1[(size_t)t * 96 + k];
    u1[t] = (float)leakyd(a);
  }
}

// ---------------- S4: fold pass2 -> vec LDS; per-thread one gate row; LSTM combine ----------------
// grid 512 (16 rows/block), block 256
__global__ __launch_bounds__(256) void k_s4(const float* __restrict__ Fp, const float* __restrict__ Gp,
                                            const float* __restrict__ v1, const float* __restrict__ u1,
                                            const float* __restrict__ rowsum, const float* __restrict__ colsum,
                                            const float* __restrict__ Wih, const float* __restrict__ Whh,
                                            const float* __restrict__ bih, const float* __restrict__ bhh,
                                            const float* __restrict__ h_in, const float* __restrict__ c_in,
                                            float* __restrict__ out, float* __restrict__ v2,
                                            float* __restrict__ u2p) {
  __shared__ float vecL[16 * 148];    // [u1(16) | Av1(32) | ATv1(32) | v1(32) | h(32)] per row
  __shared__ float gL[16 * 132];      // gates [row][128] (+4 pad)
  __shared__ float rsL[16], csL[16];
  __shared__ float hoL[16 * 17];      // h_out cols 16..31
  const int t = threadIdx.x;
  const int n0 = blockIdx.x * 16;
  if (t < 16) rsL[t] = rowsum[n0 + t];
  else if (t < 32) csL[t - 16] = colsum[n0 + t - 16];
  { const int r = t >> 4, k = t & 15; vecL[r * 148 + k] = u1[k]; }
  __syncthreads();
  // ---- Phase A: fold split-K partials into vec ----
  {
    const int r = t >> 4, q = t & 15;
    const int n = n0 + r;
    if (q < 8) {
      const int c = q * 4;
      float4 s = {0.f, 0.f, 0.f, 0.f};
      for (int p = 0; p < 32; ++p) {
        const float4 v = *(const float4*)&Fp[((size_t)p * NROW + n) * 32 + c];
        s.x += v.x; s.y += v.y; s.z += v.z; s.w += v.w;
      }
      const float rsv = rsL[r];
      float4 o = {s.x / rsv, s.y / rsv, s.z / rsv, s.w / rsv};
      *(float4*)&vecL[r * 148 + 16 + c] = o;
      *(float4*)&vecL[r * 148 + 80 + c] = *(const float4*)&v1[(size_t)n * 32 + c];
    } else {
      const int c = (q - 8) * 4;
      float4 s = {0.f, 0.f, 0.f, 0.f};
      for (int p = 0; p < 64; ++p) {
        const float4 v = *(const float4*)&Gp[((size_t)p * NROW + n) * 32 + c];
        s.x += v.x; s.y += v.y; s.z += v.z; s.w += v.w;
      }
      const float csv = csL[r];
      float4 o = {s.x / csv, s.y / csv, s.z / csv, s.w / csv};
      *(float4*)&vecL[r * 148 + 48 + c] = o;
      *(float4*)&vecL[r * 148 + 112 + c] = *(const float4*)&h_in[(size_t)n * 32 + c];
    }
  }
  __syncthreads();
  // ---- Phase B: gates. gate = t&127, 8 rows each ----
  {
    const int gate = t & 127;
    const int half = t >> 7;
    const float bias = bih[gate] + bhh[gate];
    float acc[8];
    #pragma unroll
    for (int rr = 0; rr < 8; ++rr) acc[rr] = bias;
    const float* __restrict__ Wrow = Wih + (size_t)gate * 112;
    const float* __restrict__ vbase = vecL + (half * 8) * 148;
    #pragma unroll 4
    for (int kq = 0; kq < 28; ++kq) {
      const float4 w = *(const float4*)&Wrow[kq * 4];
      #pragma unroll
      for (int rr = 0; rr < 8; ++rr) {
        const float4 v = *(const float4*)&vbase[rr * 148 + kq * 4];
        acc[rr] += w.x * v.x + w.y * v.y + w.z * v.z + w.w * v.w;
      }
    }
    const float* __restrict__ Hrow = Whh + (size_t)gate * 32;
    #pragma unroll 4
    for (int kq = 0; kq < 8; ++kq) {
      const float4 w = *(const float4*)&Hrow[kq * 4];
      #pragma unroll
      for (int rr = 0; rr < 8; ++rr) {
        const float4 v = *(const float4*)&vbase[rr * 148 + 112 + kq * 4];
        acc[rr] += w.x * v.x + w.y * v.y + w.z * v.z + w.w * v.w;
      }
    }
    #pragma unroll
    for (int rr = 0; rr < 8; ++rr) gL[(half * 8 + rr) * 132 + gate] = acc[rr];
  }
  __syncthreads();
  // ---- Phase C: LSTM combine, outputs ----
  #pragma unroll
  for (int it = 0; it < 2; ++it) {
    const int w = it * 256 + t;
    const int r = w >> 5, j = w & 31;
    const int n = n0 + r;
    const float iv = gL[r * 132 + j];
    const float fv = gL[r * 132 + 32 + j];
    const float gv = gL[r * 132 + 64 + j];
    const float ov = gL[r * 132 + 96 + j];
    const float cv = c_in[(size_t)n * 32 + j];
    const float cn = sigf(fv) * cv + sigf(iv) * tanhf(gv);
    const float hn = sigf(ov) * tanhf(cn);
    out[8192 + (size_t)n * 32 + j] = hn;
    out[8192 + 262144 + (size_t)n * 32 + j] = cn;
    if (j < 16) v2[(size_t)n * 16 + j] = leaky(hn);
    else hoL[r * 17 + (j - 16)] = hn;
  }
  __syncthreads();
  if (t < 16) {
    float s = 0.f;
    for (int r2 = 0; r2 < 16; ++r2) s += hoL[r2 * 17 + t];
    u2p[(size_t)blockIdx.x * 16 + t] = s;
  }
}

// ---------------- S6: u2 inline; fold pass3 (f64, stride 16), layer3 (f64), gumbel-argmax ----------------
// grid 128 (64 rows/block), block 256
// RNG: JAX partitionable threefry: (o0,o1)=threefry2x32(key,(0,m)); bits = o0^o1. VERIFIED r4.
__global__ __launch_bounds__(256) void k_s6(const float* __restrict__ Fp, const float* __restrict__ Gp,
                                            const float* __restrict__ v2, const float* __restrict__ u2p,
                                            const float* __restrict__ rowsum, const float* __restrict__ colsum,
                                            const float* __restrict__ W3, const float* __restrict__ b3,
                                            float* __restrict__ out) {
  __shared__ float l3L[64 * 68];
  __shared__ float w3L[192];
  __shared__ float b3L[3];
  __shared__ float u2L[16];
  __shared__ double lgL[64 * 4];
  __shared__ float rsL[64], csL[64];
  const int t = threadIdx.x;
  const int n0 = blockIdx.x * 64;
  if (t < 192) w3L[t] = W3[t];
  if (t < 3) b3L[t] = b3[t];
  if (t < 64) rsL[t] = rowsum[n0 + t];
  else if (t < 128) csL[t - 64] = colsum[n0 + t - 64];
  else if (t >= 240) {
    // u2 fold (was k_s5): 16 threads, 512 partials each, f64
    const int j = t - 240;
    double s = 0.;
    for (int b = 0; b < 512; ++b) s += (double)u2p[(size_t)b * 16 + j];
    u2L[j] = (float)leakyd(s * (1.0 / 8192.0));
  }
  __syncthreads();
  {
    const int r = t >> 2, q = t & 3;
    const int n = n0 + r;
    if (q == 0) {
      #pragma unroll
      for (int cc = 0; cc < 4; ++cc) *(float4*)&l3L[r * 68 + cc * 4] = *(const float4*)&u2L[cc * 4];
    } else if (q == 1) {
      const double rsv = (double)rsL[r];
      #pragma unroll
      for (int cc = 0; cc < 4; ++cc) {
        const int c = cc * 4;
        double s[4] = {0., 0., 0., 0.};
        for (int p = 0; p < 32; ++p) {
          const float4 v = *(const float4*)&Fp[((size_t)p * NROW + n) * 16 + c];
          s[0] += v.x; s[1] += v.y; s[2] += v.z; s[3] += v.w;
        }
        #pragma unroll
        for (int q2 = 0; q2 < 4; ++q2) l3L[r * 68 + 16 + c + q2] = (float)(s[q2] / rsv);
      }
    } else if (q == 2) {
      const double csv = (double)csL[r];
      #pragma unroll
      for (int cc = 0; cc < 4; ++cc) {
        const int c = cc * 4;
        double s[4] = {0., 0., 0., 0.};
        for (int p = 0; p < 64; ++p) {
          const float4 v = *(const float4*)&Gp[((size_t)p * NROW + n) * 16 + c];
          s[0] += v.x; s[1] += v.y; s[2] += v.z; s[3] += v.w;
        }
        #pragma unroll
        for (int q2 = 0; q2 < 4; ++q2) l3L[r * 68 + 32 + c + q2] = (float)(s[q2] / csv);
      }
    } else {
      #pragma unroll
      for (int cc = 0; cc < 4; ++cc)
        *(float4*)&l3L[r * 68 + 48 + cc * 4] = *(const float4*)&v2[(size_t)n * 16 + cc * 4];
    }
  }
  __syncthreads();
  {
    const int r = t >> 2, q = t & 3;
    if (q < 3) {
      double a = (double)b3L[q];
      for (int k = 0; k < 64; ++k) a += (double)l3L[r * 68 + k] * (double)w3L[q * 64 + k];
      lgL[r * 4 + q] = 2.0 * tanh(a);
    }
  }
  __syncthreads();
  if ((t & 3) == 0) {
    const int r = t >> 2;
    const int n = n0 + r;
    int best = 0;
    double bv = -1.0e300;
    #pragma unroll
    for (int j = 0; j < 3; ++j) {
      const uint32_t m = (uint32_t)(n * 3 + j);
      uint32_t o0, o1;
      threefry(0u, m, o0, o1);           // partitionable: counter64 = m -> (hi=0, lo=m)
      const uint32_t bits = o0 ^ o1;     // 32-bit output word
      const float f = __uint_as_float((bits >> 9) | 0x3f800000u) - 1.0f;
      const double u = fmax((double)f, 1.17549435e-38);
      const double g = -log(-log(u));
      const double val = g + lgL[r * 4 + j];
      if (val > bv) { bv = val; best = j; }
    }
    out[n] = (float)best - 1.0f;
  }
}

// ---------------- launch ----------------
extern "C" void kernel_launch(void* const* d_in, const int* in_sizes, int n_in,
                              void* d_out, int out_size, void* d_ws, size_t ws_size,
                              hipStream_t stream) {
  const float* adj = (const float*)d_in[0];
  const float* x   = (const float*)d_in[1];
  const float* h   = (const float*)d_in[2];
  const float* c   = (const float*)d_in[3];
  const float* W1  = (const float*)d_in[4];
  const float* b1  = (const float*)d_in[5];
  const float* uW1 = (const float*)d_in[6];
  const float* ub1 = (const float*)d_in[7];
  const float* Wih = (const float*)d_in[8];
  const float* Whh = (const float*)d_in[9];
  const float* bih = (const float*)d_in[10];
  const float* bhh = (const float*)d_in[11];
  const float* W3  = (const float*)d_in[12];
  const float* b3  = (const float*)d_in[13];
  float* out = (float*)d_out;
  float* ws  = (float*)d_ws;

  float* Fp  = ws + W_FP;
  float* Gp  = ws + W_GP;
  float* rsP = ws + W_RSP;
  float* csP = ws + W_CSP;
  float* rs  = ws + W_RS;
  float* cs  = ws + W_CS;
  float* v1  = ws + W_V1;
  float* v2  = ws + W_V2;
  float* u1  = ws + W_U1;
  float* mlp = ws + W_MLP;
  float* u2p = ws + W_U2P;

  // ---- pass 1: adj @ x AND adj.T @ x (+ row/col sums) ----
  k_gemm<32, true><<<dim3(64, 32), 256, 0, stream>>>(adj, x, Fp, Gp, rsP, csP);
  k_s1<<<256, 256, 0, stream>>>(Fp, rsP, Gp, csP, x, W1, b1, rs, cs, v1, mlp);
  k_s2<<<1, 128, 0, stream>>>(mlp, uW1, ub1, u1);

  // ---- pass 2: adj @ v1 AND adj.T @ v1 ; LSTM ----
  k_gemm<32, false><<<dim3(64, 32), 256, 0, stream>>>(adj, v1, Fp, Gp, nullptr, nullptr);
  k_s4<<<512, 256, 0, stream>>>(Fp, Gp, v1, u1, rs, cs, Wih, Whh, bih, bhh, h, c, out, v2, u2p);

  // ---- pass 3: adj @ v2 AND adj.T @ v2 (stride 16) ; layer3 + sampling (u2 inline) ----
  k_gemm<16, false><<<dim3(64, 32), 256, 0, stream>>>(adj, v2, Fp, Gp, nullptr, nullptr);
  k_s6<<<128, 256, 0, stream>>>(Fp, Gp, v2, u2p, rs, cs, W3, b3, out);
}